// Round 4
// baseline (2162.292 us; speedup 1.0000x reference)
//
#include <hip/hip_runtime.h>
#include <math.h>

// ---------------------------------------------------------------------------
// WhereValuePredictor on MI355X — round 9: sentinel-poll LSTM, indexing fixed.
// r8 failed (NaN): three indexing bugs in phase C — slab row treated as 512B
// instead of 1024B (poll read wrong addresses), hR staged OOB (clobbered
// preS/Tr -> NaN), clear covered only half of each 32-unit stripe. Protocol
// unchanged otherwise: h in (-1,1) strictly -> bf16 0x7FC0 (NaN) is an
// impossible value -> per-ushort validity sentinel; producer clears the slab
// it will write at t+1 during step t (commit enforced by explicit vmcnt(0)
// in E before h stores); consumer polls data chunks directly. Hardening:
// 4 rotating slabs per dir (cleared slab holds h(t-3), read two
// barrier-chains ago) + compiler fence so clears can't hoist above the poll.
// Raw s_barrier + lgkmcnt(0) only on the critical path; h stores
// fire-and-forget; out stores in the poll shadow.
// ---------------------------------------------------------------------------

using f32x4 = __attribute__((ext_vector_type(4))) float;
using s16x8 = __attribute__((ext_vector_type(8))) short;
typedef unsigned long long ulong_t;

#define ASYNC_COPY16(gsrc, ldst)                                               \
  __builtin_amdgcn_global_load_lds(                                            \
      (const __attribute__((address_space(1))) void*)(gsrc),                   \
      (__attribute__((address_space(3))) void*)(ldst), 16, 0, 0)

static __device__ __forceinline__ float sigm(float x) {
  return 1.0f / (1.0f + expf(-x));
}

static __device__ __forceinline__ unsigned short f2b_one(float x) {
  unsigned int u = __float_as_uint(x);
  u = (u + 0x7FFFu + ((u >> 16) & 1u)) >> 16;  // RNE
  return (unsigned short)u;
}

// any 16-bit lane of x equal to zero?  (exact, no false positives)
static __device__ __forceinline__ bool haszero16(ulong_t x) {
  return ((x - 0x0001000100010001ull) & ~x & 0x8000800080008000ull) != 0ull;
}

#define SENT64 0x7FC07FC07FC07FC0ull

// ------------------------- fp32 -> bf16 convert ----------------------------
__global__ __launch_bounds__(256) void f2b_kernel(
    const float* __restrict__ in, unsigned short* __restrict__ out, int n4)
{
  const int i = blockIdx.x * 256 + threadIdx.x;
  if (i >= n4) return;
  const float4 v = ((const float4*)in)[i];
  ushort4 r;
  r.x = f2b_one(v.x); r.y = f2b_one(v.y);
  r.z = f2b_one(v.z); r.w = f2b_one(v.w);
  ((ushort4*)out)[i] = r;
}

// ------------------------- masks -------------------------------------------
__global__ __launch_bounds__(256) void mask_kernel(
    const float* __restrict__ qe, const float* __restrict__ pce,
    float* __restrict__ qmask, float* __restrict__ cmask)
{
  const int w = threadIdx.x >> 6;
  const int lane = threadIdx.x & 63;
  const int row = blockIdx.x * 4 + w;  // 0..9215
  const float* src = (row < 4096) ? (qe + (size_t)row * 1024)
                                  : (pce + (size_t)(row - 4096) * 1024);
  float s = 0.f;
#pragma unroll
  for (int j = 0; j < 16; ++j) s += fabsf(src[lane + j * 64]);
#pragma unroll
  for (int off = 32; off > 0; off >>= 1) s += __shfl_down(s, off, 64);
  if (lane == 0) {
    const float m = (s != 0.f) ? 1.f : 0.f;
    if (row < 4096) qmask[row] = m;
    else cmask[row - 4096] = m;
  }
}

// ------------------------- bf16 MFMA GEMM (m97-style) ----------------------
__global__ __launch_bounds__(256) void mfma_gemm_kernel(
    const unsigned short* __restrict__ X, const unsigned short* __restrict__ W,
    const float* __restrict__ bias, float* __restrict__ C,
    int K, int ldx, int ldw, int k0w, int ldc, int c0)
{
  __shared__ unsigned short As[128 * 32];
  __shared__ unsigned short Bs[128 * 32];
  const int tid = threadIdx.x;
  const int w = tid >> 6;
  const int l = tid & 63;
  const int m0 = blockIdx.y * 128;
  const int n0 = blockIdx.x * 128;
  const int wm = (w >> 1) * 64;
  const int wn = (w & 1) * 64;

  const unsigned short* xg =
      X + (size_t)(m0 + w * 32 + (l >> 2)) * ldx + (l & 3) * 8;
  const unsigned short* wgp =
      W + (size_t)(n0 + w * 32 + (l >> 2)) * ldw + k0w + (l & 3) * 8;
  unsigned short* asb = As + w * 1024;
  unsigned short* bsb = Bs + w * 1024;

  const int fr = l & 15;
  const int fq = l >> 4;
  const unsigned short* aRd = As + (wm + fr) * 32 + fq * 8;
  const unsigned short* bRd = Bs + (wn + fr) * 32 + fq * 8;

  f32x4 acc[4][4];
#pragma unroll
  for (int i = 0; i < 4; ++i)
#pragma unroll
    for (int j = 0; j < 4; ++j) acc[i][j] = (f32x4){0.f, 0.f, 0.f, 0.f};

  for (int k0 = 0; k0 < K; k0 += 32) {
    ASYNC_COPY16(xg + k0, asb);
    ASYNC_COPY16(xg + (size_t)16 * ldx + k0, asb + 512);
    ASYNC_COPY16(wgp + k0, bsb);
    ASYNC_COPY16(wgp + (size_t)16 * ldw + k0, bsb + 512);
    __syncthreads();
    s16x8 a[4], b[4];
#pragma unroll
    for (int i = 0; i < 4; ++i) a[i] = *(const s16x8*)(aRd + i * 512);
#pragma unroll
    for (int j = 0; j < 4; ++j) b[j] = *(const s16x8*)(bRd + j * 512);
#pragma unroll
    for (int i = 0; i < 4; ++i)
#pragma unroll
      for (int j = 0; j < 4; ++j)
        acc[i][j] = __builtin_amdgcn_mfma_f32_16x16x32_bf16(
            a[i], b[j], acc[i][j], 0, 0, 0);
    __syncthreads();
  }

#pragma unroll
  for (int j = 0; j < 4; ++j) {
    const int col = n0 + wn + j * 16 + fr;
    const float bj = bias ? bias[col] : 0.f;
#pragma unroll
    for (int i = 0; i < 4; ++i) {
      const int row = m0 + wm + i * 16 + fq * 4;
#pragma unroll
      for (int r = 0; r < 4; ++r)
        C[(size_t)(row + r) * ldc + c0 + col] = acc[i][j][r] + bj;
    }
  }
}

// ------------------------- generic fp32 GEMM (small tails) ------------------
__global__ __launch_bounds__(256) void gemm_kernel(
    const float* __restrict__ X, const float* __restrict__ W,
    const float* __restrict__ bias, float* __restrict__ C,
    int M, int N, int K, int ldx, int ldw, int k0w, int ldc, int c0)
{
  __shared__ float Xs[16][68];
  __shared__ float Ws[16][68];
  const int tid = threadIdx.x;
  const int m0 = blockIdx.y * 64;
  const int n0 = blockIdx.x * 64;
  const int lrow = tid >> 2;
  const int lkk = (tid & 3) << 2;
  const float* Xp = X + (size_t)(m0 + lrow) * ldx + lkk;
  const float* Wp = W + (size_t)(n0 + lrow) * ldw + k0w + lkk;
  const int tm = (tid >> 4) << 2;
  const int tn = (tid & 15) << 2;
  float acc[4][4];
#pragma unroll
  for (int i = 0; i < 4; ++i)
#pragma unroll
    for (int j = 0; j < 4; ++j) acc[i][j] = 0.f;

  for (int k0 = 0; k0 < K; k0 += 16) {
    const float4 xv = *(const float4*)(Xp + k0);
    const float4 wv = *(const float4*)(Wp + k0);
    Xs[lkk + 0][lrow] = xv.x; Xs[lkk + 1][lrow] = xv.y;
    Xs[lkk + 2][lrow] = xv.z; Xs[lkk + 3][lrow] = xv.w;
    Ws[lkk + 0][lrow] = wv.x; Ws[lkk + 1][lrow] = wv.y;
    Ws[lkk + 2][lrow] = wv.z; Ws[lkk + 3][lrow] = wv.w;
    __syncthreads();
#pragma unroll
    for (int kk = 0; kk < 16; ++kk) {
      const float4 a4 = *(const float4*)&Xs[kk][tm];
      const float4 b4 = *(const float4*)&Ws[kk][tn];
      const float av[4] = {a4.x, a4.y, a4.z, a4.w};
      const float bv[4] = {b4.x, b4.y, b4.z, b4.w};
#pragma unroll
      for (int i = 0; i < 4; ++i)
#pragma unroll
        for (int j = 0; j < 4; ++j) acc[i][j] += av[i] * bv[j];
    }
    __syncthreads();
  }
  float bvv[4] = {0.f, 0.f, 0.f, 0.f};
  if (bias) {
#pragma unroll
    for (int j = 0; j < 4; ++j) bvv[j] = bias[n0 + tn + j];
  }
#pragma unroll
  for (int i = 0; i < 4; ++i)
#pragma unroll
    for (int j = 0; j < 4; ++j)
      C[(size_t)(m0 + tm + i) * ldc + c0 + n0 + tn + j] = acc[i][j] + bvv[j];
}

// ------------------------- persistent LSTM scan (sentinel-poll) -------------
// Grid (32, BG): blockIdx.x = dir*16 + unit-slice w (32 units, 8 waves x 4).
// blockIdx.y = batch group (NT 16-row tiles). Per-dir 4-slab rotation:
// h(t) -> slab t%4 (cleared by its producer at step t-1); consumer reads
// h(t-1) from slab (t+3)%4; producer clears slab (t+1)%4 (holds h(t-3),
// last read at C(t-2) — two barrier-chains of slack). Per step:
//   C{poll h(t-1) -> hR; fence; clear slab (t+1)%4; pv loads} B1
//   D{MFMA gates + state -> hS, hn regs} B2
//   E{preS<-pv; vmcnt(0) commits clears; h stores; out stores}.
// B1/B2 are raw s_barrier + lgkmcnt(0) (no vmcnt drain on critical path).
template <int NT>
__global__ __launch_bounds__(512, 2) void lstm_seq_kernel(
    const float* __restrict__ pre,           // [Bn][T][4096]
    const unsigned short* __restrict__ whh,  // bf16 [2 dirs][2048][512]
    unsigned short* __restrict__ hbuf,       // bf16 [2 dirs][4 slabs][640][512]
    float* __restrict__ out,                 // [Bn][T][1024]
    int T, unsigned* __restrict__ bar, unsigned base)
{
  __shared__ float preS[NT][4][16][34];      // [nt][gate][n][unit+pad]
  __shared__ float Tr[8][4][4][16];          // [wave][gate][du][n] wave-local
  __shared__ unsigned short hS[NT * 16][36]; // [n_local][unit+pad] (write stg)
  __shared__ unsigned short hR[NT * 16][520];// [n_local][unit] staged h read
  const int tid = threadIdx.x;               // 0..511
  const int v = tid >> 6;                    // wave 0..7
  const int l = tid & 63;
  const int d = blockIdx.x >> 4;
  const int w = blockIdx.x & 15;             // slice: units w*32..+31
  const int bg = blockIdx.y;
  const int fr = l & 15;
  const int fq = l >> 4;
  const int ubase = w * 32;
  const int unit = ubase + v * 4 + fq;
  const int nbase = bg * (NT * 16);
  const size_t SLOT = (size_t)640 * 512;
  unsigned* ctr = bar + (d * 8 + bg) * 16;   // 64B-spaced counters
  unsigned short* sl = hbuf + (size_t)d * 4 * SLOT;  // this dir's 4 slabs

  // A-frags: MFMA A row m=fr -> whh row (m>>2)*512 + ubase + v*4 + (m&3)
  s16x8 afr[16];
  {
    const unsigned short* arow = whh + (size_t)d * 2048 * 512 +
        ((size_t)(fr >> 2) * 512 + ubase + v * 4 + (fr & 3)) * 512 + fq * 8;
#pragma unroll
    for (int kk = 0; kk < 16; ++kk)
      afr[kk] = *(const s16x8*)(arow + kk * 32);
  }

  float creg[NT];
#pragma unroll
  for (int i = 0; i < NT; ++i) creg[i] = 0.f;

  // staging thread mapping: one float4 per thread per nt
  const int sc = tid & 7;
  const int sn = (tid >> 3) & 15;
  const int sg = tid >> 7;

  // ---- prologue: sentinel-clear own stripe in all 4 slabs ----
  // stripe = rows [nbase, nbase+NT*16) x units [ubase, ubase+32)
  // row stride = 512 ushorts = 128 ulongs; stripe row = 8 ulongs.
  for (int s = 0; s < 4; ++s) {
    ulong_t* cb = (ulong_t*)(sl + (size_t)s * SLOT + (size_t)nbase * 512 + ubase);
    for (int i = tid; i < NT * 16 * 8; i += 512)
      __hip_atomic_store(cb + (size_t)(i >> 3) * 128 + (i & 7), SENT64,
                         __ATOMIC_RELAXED, __HIP_MEMORY_SCOPE_AGENT);
  }
  // ---- prologue: stage pre for t=0 ----
  {
    const int tt0 = d ? (T - 1) : 0;
#pragma unroll
    for (int nt = 0; nt < NT; ++nt) {
      const int n = nbase + nt * 16 + sn;
      const float4 pv = *(const float4*)(
          pre + ((size_t)n * T + tt0) * 4096 + d * 2048 + sg * 512 + ubase +
          sc * 4);
      *(float4*)&preS[nt][sg][sn][sc * 4] = pv;
    }
  }
  __syncthreads();  // drains clears (vmcnt0 per wave) + preS lgkm
  // ---- launch-entry barrier: all 16 WGs of (d,bg) cleared their stripes ----
  if (tid == 0) {
    __hip_atomic_fetch_add(ctr, 1u, __ATOMIC_RELAXED,
                           __HIP_MEMORY_SCOPE_AGENT);
    const unsigned target = base + 16u;
    long spins = 0;
    while (__hip_atomic_load(ctr, __ATOMIC_RELAXED,
                             __HIP_MEMORY_SCOPE_AGENT) < target) {
      __builtin_amdgcn_s_sleep(1);
      if (++spins > 2000000L) break;  // safety valve
    }
  }
  __syncthreads();

  float hnreg[NT];
  for (int t = 0; t < T; ++t) {
    const int tt = d ? (T - 1 - t) : t;
    const unsigned short* rd = sl + (size_t)((t + 3) & 3) * SLOT;  // h(t-1)
    unsigned short* wr = sl + (size_t)(t & 3) * SLOT;              // h(t)

    // ---- C: poll h(t-1) chunks until sentinel-free ----
    // chunk = 16B; 64 chunks per 1024B row; cid in [0, 1024*NT)
    ulong_t u[4 * NT];
    if (t > 0) {
      const ulong_t* hq = (const ulong_t*)rd + (size_t)nbase * 128;
      bool ok = false;
      int it = 0;
      while (!ok && it < 1000000) {
#pragma unroll
        for (int i = 0; i < 2 * NT; ++i) {
          const int cid = i * 512 + tid;                 // 16B chunk id
          const ulong_t* p = hq + (size_t)(cid >> 6) * 128 + (cid & 63) * 2;
          u[2 * i] = __hip_atomic_load(p, __ATOMIC_RELAXED,
                                       __HIP_MEMORY_SCOPE_AGENT);
          u[2 * i + 1] = __hip_atomic_load(p + 1, __ATOMIC_RELAXED,
                                           __HIP_MEMORY_SCOPE_AGENT);
        }
        bool bad = false;
#pragma unroll
        for (int i = 0; i < 4 * NT; ++i)
          if (haszero16(u[i] ^ SENT64)) bad = true;
        ok = !bad;
        ++it;
        if (!ok && it > 8) __builtin_amdgcn_s_sleep(1);
      }
#pragma unroll
      for (int i = 0; i < 2 * NT; ++i) {
        const int cid = i * 512 + tid;
        ulong_t* dst = (ulong_t*)&hR[cid >> 6][(cid & 63) * 8];
        dst[0] = u[2 * i];
        dst[1] = u[2 * i + 1];
      }
    }
    // compiler fence: clears below must not hoist above the poll
    asm volatile("" ::: "memory");
    // ---- clear slab (t+1)%4 own stripe (holds h(t-3), read at C(t-2));
    //      committed before E(t+1) writes via the vmcnt(0) in E(t) ----
    {
      ulong_t* cb = (ulong_t*)(sl + (size_t)((t + 1) & 3) * SLOT +
                               (size_t)nbase * 512 + ubase);
      for (int i = tid; i < NT * 16 * 8; i += 512)
        __hip_atomic_store(cb + (size_t)(i >> 3) * 128 + (i & 7), SENT64,
                           __ATOMIC_RELAXED, __HIP_MEMORY_SCOPE_AGENT);
    }
    // ---- pv prefetch: pre(t+1) into registers ----
    float4 pv[NT];
    if (t + 1 < T) {
      const int ttn = d ? (T - 2 - t) : (t + 1);
#pragma unroll
      for (int nt = 0; nt < NT; ++nt) {
        const int n = nbase + nt * 16 + sn;
        pv[nt] = *(const float4*)(
            pre + ((size_t)n * T + ttn) * 4096 + d * 2048 + sg * 512 + ubase +
            sc * 4);
      }
    }
    // ---- B1: hR (and E(t-1)'s preS writes) visible to all waves ----
    asm volatile("s_waitcnt lgkmcnt(0)" ::: "memory");
    __builtin_amdgcn_s_barrier();
    __builtin_amdgcn_sched_barrier(0);

    // ---- D: gates + state update ----
#pragma unroll
    for (int nt = 0; nt < NT; ++nt) {
      f32x4 acc = (f32x4){0.f, 0.f, 0.f, 0.f};
      if (t > 0) {
        const unsigned short* bRd = &hR[nt * 16 + fr][fq * 8];
#pragma unroll
        for (int kk = 0; kk < 16; ++kk) {
          const s16x8 bv = *(const s16x8*)(bRd + kk * 32);
          acc = __builtin_amdgcn_mfma_f32_16x16x32_bf16(afr[kk], bv, acc,
                                                        0, 0, 0);
        }
      }
      // wave-local transpose (C row fq*4+r -> gate fq, du r; col fr -> n)
#pragma unroll
      for (int r = 0; r < 4; ++r) Tr[v][fq][r][fr] = acc[r];
      const int uu = v * 4 + fq;
      const float gi = Tr[v][0][fq][fr] + preS[nt][0][fr][uu];
      const float gf = Tr[v][1][fq][fr] + preS[nt][1][fr][uu];
      const float gg = Tr[v][2][fq][fr] + preS[nt][2][fr][uu];
      const float go = Tr[v][3][fq][fr] + preS[nt][3][fr][uu];
      const float cn = sigm(gf) * creg[nt] + sigm(gi) * tanhf(gg);
      const float hn = sigm(go) * tanhf(cn);
      creg[nt] = cn;
      hnreg[nt] = hn;
      hS[nt * 16 + fr][uu] = f2b_one(hn);
    }
    // ---- B2: hS ready; preS fully consumed; hR consumed ----
    asm volatile("s_waitcnt lgkmcnt(0)" ::: "memory");
    __builtin_amdgcn_s_barrier();
    __builtin_amdgcn_sched_barrier(0);

    // ---- E: preS <- pv, drain older vmem (clears!), then h + out stores ----
    if (t + 1 < T) {
#pragma unroll
      for (int nt = 0; nt < NT; ++nt)
        *(float4*)&preS[nt][sg][sn][sc * 4] = pv[nt];
    }
    asm volatile("s_waitcnt vmcnt(0)" ::: "memory");  // clears committed
    {
      const int un = tid & 7;       // ulong within 32-unit slice
      const int nl = tid >> 3;      // 0..63
      for (int p = nl; p < NT * 16; p += 64) {
        const ulong_t val = *(const ulong_t*)&hS[p][un * 4];
        __hip_atomic_store(
            (ulong_t*)(wr + (size_t)(nbase + p) * 512 + ubase) + un, val,
            __ATOMIC_RELAXED, __HIP_MEMORY_SCOPE_AGENT);
      }
    }
#pragma unroll
    for (int nt = 0; nt < NT; ++nt) {
      const int n = nbase + nt * 16 + fr;
      out[((size_t)n * T + tt) * 1024 + d * 512 + unit] = hnreg[nt];
    }
  }
}

// ------------------------- column attention pool ----------------------------
__global__ __launch_bounds__(256) void colpool_kernel(
    const float* __restrict__ cenc, const float* __restrict__ caw,
    const float* __restrict__ cab, const float* __restrict__ cmask,
    float* __restrict__ colh)
{
  __shared__ float part[8][33];
  __shared__ float wbuf[8];
  const int p = blockIdx.x;
  const int t = threadIdx.x >> 5;
  const int ln = threadIdx.x & 31;
  const float* row = cenc + ((size_t)p * 8 + t) * 1024;
  float s = 0.f;
  for (int j = ln; j < 1024; j += 32) s += row[j] * caw[j];
  part[t][ln] = s;
  __syncthreads();
  if (threadIdx.x < 8) {
    float lg = 0.f;
    for (int i = 0; i < 32; ++i) lg += part[threadIdx.x][i];
    lg += cab[0];
    wbuf[threadIdx.x] = (cmask[p * 8 + threadIdx.x] > 0.f) ? lg : -INFINITY;
  }
  __syncthreads();
  if (threadIdx.x == 0) {
    float mx = -INFINITY;
    for (int i = 0; i < 8; ++i) mx = fmaxf(mx, wbuf[i]);
    float e[8];
    float sum = 0.f;
    for (int i = 0; i < 8; ++i) { e[i] = expf(wbuf[i] - mx); sum += e[i]; }
    for (int i = 0; i < 8; ++i) wbuf[i] = e[i] / sum;
  }
  __syncthreads();
  for (int h = threadIdx.x; h < 1024; h += 256) {
    float a = 0.f;
#pragma unroll
    for (int i = 0; i < 8; ++i) a += wbuf[i] * cenc[((size_t)p * 8 + i) * 1024 + h];
    colh[(size_t)p * 1024 + h] = a;
  }
}

// ------------------------- gather observed ----------------------------------
__global__ __launch_bounds__(256) void gather_kernel(
    const float* __restrict__ colh, const int* __restrict__ gold_num,
    const int* __restrict__ gold_cols, const int* __restrict__ ncol,
    float* __restrict__ obs)
{
  const int idx = blockIdx.x * 256 + threadIdx.x;
  const int h = idx & 1023;
  const int k = (idx >> 10) & 3;
  const int b = idx >> 12;
  int gn = gold_num[b];
  if (gn > 4) gn = 4;
  const float m = (k < gn) ? 1.f : 0.f;
  const int col = gold_cols[b * 4 + k];
  const int NC = ncol[0];
  obs[idx] = m * colh[(size_t)(b * NC + col) * 1024 + h];
}

// ------------------------- fused attention (per b,k) ------------------------
__global__ __launch_bounds__(128) void attn_kernel(
    const float* __restrict__ akey, const float* __restrict__ qenc,
    const float* __restrict__ qmask, float* __restrict__ qhid)
{
  __shared__ float ak[1024];
  __shared__ float red[128];
  __shared__ float at[128];
  const int bk = blockIdx.x;
  const int b = bk >> 2;
  const int tid = threadIdx.x;
  for (int i = tid; i < 1024; i += 128) ak[i] = akey[(size_t)bk * 1024 + i];
  __syncthreads();
  const float* qrow = qenc + ((size_t)b * 128 + tid) * 1024;
  float s = 0.f;
  for (int hh = 0; hh < 1024; hh += 4) {
    const float4 qv = *(const float4*)(qrow + hh);
    s += ak[hh] * qv.x + ak[hh + 1] * qv.y + ak[hh + 2] * qv.z + ak[hh + 3] * qv.w;
  }
  s = (qmask[b * 128 + tid] > 0.f) ? s : -INFINITY;
  at[tid] = s;
  red[tid] = s;
  __syncthreads();
  for (int off = 64; off > 0; off >>= 1) {
    if (tid < off) red[tid] = fmaxf(red[tid], red[tid + off]);
    __syncthreads();
  }
  const float mx = red[0];
  __syncthreads();
  const float e = expf(at[tid] - mx);
  red[tid] = e;
  __syncthreads();
  for (int off = 64; off > 0; off >>= 1) {
    if (tid < off) red[tid] += red[tid + off];
    __syncthreads();
  }
  const float inv = 1.f / red[0];
  __syncthreads();
  at[tid] = e * inv;
  __syncthreads();
  for (int h = tid; h < 1024; h += 128) {
    float a = 0.f;
    for (int q = 0; q < 128; ++q)
      a += at[q] * qenc[((size_t)b * 128 + q) * 1024 + h];
    qhid[(size_t)bk * 1024 + h] = a;
  }
}

// ------------------------- final epilogue -----------------------------------
__global__ __launch_bounds__(64) void final_kernel(
    const float* __restrict__ A, const float* __restrict__ Bm,
    const float* __restrict__ w2, const float* __restrict__ b2,
    const int* __restrict__ gold_num, const float* __restrict__ qmask,
    float* __restrict__ out)
{
  const int bkq = blockIdx.x;
  const int q = bkq & 127;
  const int k = (bkq >> 7) & 3;
  const int b = bkq >> 9;
  int gn = gold_num[b];
  if (gn > 4) gn = 4;
  const bool act = (k < gn) && (qmask[b * 128 + q] > 0.f);
  const int lane = threadIdx.x;
  const int obase = (b * 4 + k) * 128 + q;
  if (!act) {
    if (lane == 0) {
      out[obase] = -1e30f;          // finite sentinel (ref has -inf; see r1)
      out[16384 + obase] = -1e30f;
    }
    return;
  }
  const float* Ar = A + ((size_t)b * 128 + q) * 1024;
  const float* Br = Bm + (size_t)(b * 4 + k) * 1024;
  float s0 = 0.f, s1 = 0.f;
  for (int o = lane; o < 1024; o += 64) {
    const float v = tanhf(Ar[o] + Br[o]);
    s0 += v * w2[o];
    s1 += v * w2[1024 + o];
  }
#pragma unroll
  for (int off = 32; off > 0; off >>= 1) {
    s0 += __shfl_down(s0, off, 64);
    s1 += __shfl_down(s1, off, 64);
  }
  if (lane == 0) {
    out[obase] = s0 + b2[0];
    out[16384 + obase] = s1 + b2[1];
  }
}

// ---------------------------------------------------------------------------
extern "C" void kernel_launch(void* const* d_in, const int* in_sizes, int n_in,
                              void* d_out, int out_size, void* d_ws, size_t ws_size,
                              hipStream_t stream)
{
  const float* qe      = (const float*)d_in[0];
  const float* pce     = (const float*)d_in[1];
  const int* gold_num  = (const int*)d_in[2];
  const int* gold_cols = (const int*)d_in[3];
  const int* ncol      = (const int*)d_in[5];
  const float* q_Wih   = (const float*)d_in[6];
  const float* q_Whh   = (const float*)d_in[7];
  const float* q_b     = (const float*)d_in[8];
  const float* c_Wih   = (const float*)d_in[9];
  const float* c_Whh   = (const float*)d_in[10];
  const float* c_b     = (const float*)d_in[11];
  const float* caw     = (const float*)d_in[12];
  const float* cab     = (const float*)d_in[13];
  const float* obaW    = (const float*)d_in[14];
  const float* obab    = (const float*)d_in[15];
  const float* obcW    = (const float*)d_in[16];
  const float* obcb    = (const float*)d_in[17];
  const float* qpW     = (const float*)d_in[18];
  const float* qpb     = (const float*)d_in[19];
  const float* o1W     = (const float*)d_in[20];
  const float* o1b     = (const float*)d_in[21];
  const float* o2W     = (const float*)d_in[22];
  const float* o2b     = (const float*)d_in[23];
  float* outp = (float*)d_out;

  float* ws = (float*)d_ws;
  size_t off = 0;
  float* pre  = ws + off; off += 640UL * 8 * 4096;   // also reused as A matrix
  float* bufA = ws + off; off += 640UL * 8 * 1024;
  float* bufB = ws + off; off += 640UL * 8 * 1024;
  float* colh = ws + off; off += 640UL * 1024;
  float* qmask = ws + off; off += 4096;
  float* cmask = ws + off; off += 5120;
  float* obs  = ws + off; off += 131072;
  float* akey = ws + off; off += 131072;
  float* qhid = ws + off; off += 131072;
  float* vec  = ws + off; off += 262144;
  float* Bm   = ws + off; off += 131072;
  unsigned short* xb = (unsigned short*)(ws + off); off += 2621440;  // bf16 acts
  unsigned short* wb = (unsigned short*)(ws + off); off += 2097152;  // bf16 Wih
  unsigned short* whhq = (unsigned short*)(ws + off); off += 2097152; // q_Whh bf16
  unsigned short* whhc = (unsigned short*)(ws + off); off += 2097152; // c_Whh bf16
  unsigned short* hbuf = (unsigned short*)(ws + off); off += 1310720; // 2 dirs x 4 slabs
  unsigned* bar = (unsigned*)(ws + off); off += 256;  // 16 counters x 64B
  float* Amat = pre;

  const dim3 blk(256);
  auto cvt = [&](const float* src, unsigned short* dst, int n) {
    hipLaunchKernelGGL(f2b_kernel, dim3((n / 4 + 255) / 256), blk, 0, stream,
                       src, dst, n / 4);
  };

  // counters must start at 0 every call (ws is poisoned 0xAA)
  hipMemsetAsync(bar, 0, 1024, stream);

  hipLaunchKernelGGL(mask_kernel, dim3(2304), blk, 0, stream, qe, pce, qmask, cmask);

  // recurrent weights -> bf16 (once)
  cvt(q_Whh, whhq, 4194304);
  cvt(c_Whh, whhc, 4194304);

  // ---- column biLSTM (B=640, T=8): grid (32,8), NT=5 ----
  // entry counters (d*8+bg): +16 per launch
  for (int l = 0; l < 2; ++l) {
    const float* xin = (l == 0) ? pce : bufA;
    float* enc = (l == 0) ? bufA : bufB;
    cvt(xin, xb, 5242880);
    cvt(c_Wih + (size_t)l * 4194304, wb, 4194304);
    hipLaunchKernelGGL(mfma_gemm_kernel, dim3(4096 / 128, 5120 / 128), blk, 0,
                       stream, xb, wb, c_b + l * 4096, pre,
                       1024, 1024, 1024, 0, 4096, 0);
    hipLaunchKernelGGL((lstm_seq_kernel<5>), dim3(32, 8), dim3(512), 0, stream,
                       pre, whhc + (size_t)l * 2 * 2048 * 512, hbuf, enc,
                       8, bar, (unsigned)(l * 16));
  }
  hipLaunchKernelGGL(colpool_kernel, dim3(640), blk, 0, stream,
                     bufB, caw, cab, cmask, colh);
  hipLaunchKernelGGL(gather_kernel, dim3(512), blk, 0, stream,
                     colh, gold_num, gold_cols, ncol, obs);

  // ---- question biLSTM (B=32, T=128): grid (32,1), NT=2 ----
  // entry counters (d,0): at 32 after col launches; +16 per q launch
  for (int l = 0; l < 2; ++l) {
    const float* xin = (l == 0) ? qe : bufA;
    float* enc = (l == 0) ? bufA : bufB;
    cvt(xin, xb, 4194304);
    cvt(q_Wih + (size_t)l * 4194304, wb, 4194304);
    hipLaunchKernelGGL(mfma_gemm_kernel, dim3(4096 / 128, 4096 / 128), blk, 0,
                       stream, xb, wb, q_b + l * 4096, pre,
                       1024, 1024, 1024, 0, 4096, 0);
    hipLaunchKernelGGL((lstm_seq_kernel<2>), dim3(32, 1), dim3(512), 0, stream,
                       pre, whhq + (size_t)l * 2 * 2048 * 512, hbuf, enc,
                       128, bar, (unsigned)(32 + l * 16));
  }
  const float* qenc = bufB;

  // att_key = observed @ ob_attn_W^T + b   (small, fp32 path)
  hipLaunchKernelGGL(gemm_kernel, dim3(16, 2), blk, 0, stream,
                     obs, obaW, obab, akey, 128, 1024, 1024, 1024, 1024, 0, 1024, 0);
  hipLaunchKernelGGL(attn_kernel, dim3(128), dim3(128), 0, stream,
                     akey, qenc, qmask, qhid);
  hipLaunchKernelGGL(gemm_kernel, dim3(16, 2), blk, 0, stream,
                     obs, obcW, obcb, vec, 128, 1024, 1024, 1024, 1024, 0, 2048, 0);
  hipLaunchKernelGGL(gemm_kernel, dim3(16, 2), blk, 0, stream,
                     qhid, qpW, qpb, vec, 128, 1024, 1024, 1024, 1024, 0, 2048, 1024);
  // A = qenc @ out1_W[:, :1024]^T + b1  (bf16 MFMA)
  cvt(qenc, xb, 4194304);
  cvt(o1W, wb, 3145728);
  hipLaunchKernelGGL(mfma_gemm_kernel, dim3(1024 / 128, 4096 / 128), blk, 0,
                     stream, xb, wb, o1b, Amat, 1024, 1024, 3072, 0, 1024, 0);
  // Bm = vec @ out1_W[:, 1024:]^T (fp32 path)
  hipLaunchKernelGGL(gemm_kernel, dim3(16, 2), blk, 0, stream,
                     vec, o1W, nullptr, Bm, 128, 1024, 2048, 2048, 3072, 1024, 1024, 0);
  hipLaunchKernelGGL(final_kernel, dim3(16384), dim3(64), 0, stream,
                     Amat, Bm, o2W, o2b, gold_num, qmask, outp);
}

// Round 5
// 1975.947 us; speedup vs baseline: 1.0943x; 1.0943x over previous
//
#include <hip/hip_runtime.h>
#include <math.h>

// ---------------------------------------------------------------------------
// WhereValuePredictor on MI355X — round 10: parity-tag exchange (clear-free).
// r9 post-mortem: sentinel-poll passed but regressed 489->531us: per-step
// slab clears added ~24MB coherence traffic (FETCH 51->68MB, WRITE 25->33MB)
// + an E vmcnt(0) drain. Fix: embed the tag IN the h data — bf16 mantissa
// LSB = (t/3)&1 (<=1 ulp, inside bf16 noise). 3 rotating slabs/dir, reused
// every 3 steps with alternating tag -> zero clears; poll checks LSBs and
// the successful poll IS the data load; h stores fire-and-forget. One-time
// pre-clear (LSB=1) + entry ctr barrier vs cross-launch staleness.
// Also: hR stride 520->528 (2-way max bank conflicts, was ~4-8 way, 4.7M
// SQ_LDS_BANK_CONFLICT), Tr padded [4][4][20], fast sigm/tanh via v_exp+rcp.
// ---------------------------------------------------------------------------

using f32x4 = __attribute__((ext_vector_type(4))) float;
using s16x8 = __attribute__((ext_vector_type(8))) short;
typedef unsigned long long ulong_t;

#define ASYNC_COPY16(gsrc, ldst)                                               \
  __builtin_amdgcn_global_load_lds(                                            \
      (const __attribute__((address_space(1))) void*)(gsrc),                   \
      (__attribute__((address_space(3))) void*)(ldst), 16, 0, 0)

#define LSBM 0x0001000100010001ull

static __device__ __forceinline__ float sigm(float x) {
  return __builtin_amdgcn_rcpf(1.0f + __expf(-x));
}
static __device__ __forceinline__ float tanh_f(float x) {
  return 1.0f - 2.0f * __builtin_amdgcn_rcpf(__expf(2.0f * x) + 1.0f);
}

static __device__ __forceinline__ unsigned short f2b_one(float x) {
  unsigned int u = __float_as_uint(x);
  u = (u + 0x7FFFu + ((u >> 16) & 1u)) >> 16;  // RNE
  return (unsigned short)u;
}

// ------------------------- fp32 -> bf16 convert ----------------------------
__global__ __launch_bounds__(256) void f2b_kernel(
    const float* __restrict__ in, unsigned short* __restrict__ out, int n4)
{
  const int i = blockIdx.x * 256 + threadIdx.x;
  if (i >= n4) return;
  const float4 v = ((const float4*)in)[i];
  ushort4 r;
  r.x = f2b_one(v.x); r.y = f2b_one(v.y);
  r.z = f2b_one(v.z); r.w = f2b_one(v.w);
  ((ushort4*)out)[i] = r;
}

// ------------------------- masks -------------------------------------------
__global__ __launch_bounds__(256) void mask_kernel(
    const float* __restrict__ qe, const float* __restrict__ pce,
    float* __restrict__ qmask, float* __restrict__ cmask)
{
  const int w = threadIdx.x >> 6;
  const int lane = threadIdx.x & 63;
  const int row = blockIdx.x * 4 + w;  // 0..9215
  const float* src = (row < 4096) ? (qe + (size_t)row * 1024)
                                  : (pce + (size_t)(row - 4096) * 1024);
  float s = 0.f;
#pragma unroll
  for (int j = 0; j < 16; ++j) s += fabsf(src[lane + j * 64]);
#pragma unroll
  for (int off = 32; off > 0; off >>= 1) s += __shfl_down(s, off, 64);
  if (lane == 0) {
    const float m = (s != 0.f) ? 1.f : 0.f;
    if (row < 4096) qmask[row] = m;
    else cmask[row - 4096] = m;
  }
}

// ------------------------- bf16 MFMA GEMM (m97-style) ----------------------
__global__ __launch_bounds__(256) void mfma_gemm_kernel(
    const unsigned short* __restrict__ X, const unsigned short* __restrict__ W,
    const float* __restrict__ bias, float* __restrict__ C,
    int K, int ldx, int ldw, int k0w, int ldc, int c0)
{
  __shared__ unsigned short As[128 * 32];
  __shared__ unsigned short Bs[128 * 32];
  const int tid = threadIdx.x;
  const int w = tid >> 6;
  const int l = tid & 63;
  const int m0 = blockIdx.y * 128;
  const int n0 = blockIdx.x * 128;
  const int wm = (w >> 1) * 64;
  const int wn = (w & 1) * 64;

  const unsigned short* xg =
      X + (size_t)(m0 + w * 32 + (l >> 2)) * ldx + (l & 3) * 8;
  const unsigned short* wgp =
      W + (size_t)(n0 + w * 32 + (l >> 2)) * ldw + k0w + (l & 3) * 8;
  unsigned short* asb = As + w * 1024;
  unsigned short* bsb = Bs + w * 1024;

  const int fr = l & 15;
  const int fq = l >> 4;
  const unsigned short* aRd = As + (wm + fr) * 32 + fq * 8;
  const unsigned short* bRd = Bs + (wn + fr) * 32 + fq * 8;

  f32x4 acc[4][4];
#pragma unroll
  for (int i = 0; i < 4; ++i)
#pragma unroll
    for (int j = 0; j < 4; ++j) acc[i][j] = (f32x4){0.f, 0.f, 0.f, 0.f};

  for (int k0 = 0; k0 < K; k0 += 32) {
    ASYNC_COPY16(xg + k0, asb);
    ASYNC_COPY16(xg + (size_t)16 * ldx + k0, asb + 512);
    ASYNC_COPY16(wgp + k0, bsb);
    ASYNC_COPY16(wgp + (size_t)16 * ldw + k0, bsb + 512);
    __syncthreads();
    s16x8 a[4], b[4];
#pragma unroll
    for (int i = 0; i < 4; ++i) a[i] = *(const s16x8*)(aRd + i * 512);
#pragma unroll
    for (int j = 0; j < 4; ++j) b[j] = *(const s16x8*)(bRd + j * 512);
#pragma unroll
    for (int i = 0; i < 4; ++i)
#pragma unroll
      for (int j = 0; j < 4; ++j)
        acc[i][j] = __builtin_amdgcn_mfma_f32_16x16x32_bf16(
            a[i], b[j], acc[i][j], 0, 0, 0);
    __syncthreads();
  }

#pragma unroll
  for (int j = 0; j < 4; ++j) {
    const int col = n0 + wn + j * 16 + fr;
    const float bj = bias ? bias[col] : 0.f;
#pragma unroll
    for (int i = 0; i < 4; ++i) {
      const int row = m0 + wm + i * 16 + fq * 4;
#pragma unroll
      for (int r = 0; r < 4; ++r)
        C[(size_t)(row + r) * ldc + c0 + col] = acc[i][j][r] + bj;
    }
  }
}

// ------------------------- generic fp32 GEMM (small tails) ------------------
__global__ __launch_bounds__(256) void gemm_kernel(
    const float* __restrict__ X, const float* __restrict__ W,
    const float* __restrict__ bias, float* __restrict__ C,
    int M, int N, int K, int ldx, int ldw, int k0w, int ldc, int c0)
{
  __shared__ float Xs[16][68];
  __shared__ float Ws[16][68];
  const int tid = threadIdx.x;
  const int m0 = blockIdx.y * 64;
  const int n0 = blockIdx.x * 64;
  const int lrow = tid >> 2;
  const int lkk = (tid & 3) << 2;
  const float* Xp = X + (size_t)(m0 + lrow) * ldx + lkk;
  const float* Wp = W + (size_t)(n0 + lrow) * ldw + k0w + lkk;
  const int tm = (tid >> 4) << 2;
  const int tn = (tid & 15) << 2;
  float acc[4][4];
#pragma unroll
  for (int i = 0; i < 4; ++i)
#pragma unroll
    for (int j = 0; j < 4; ++j) acc[i][j] = 0.f;

  for (int k0 = 0; k0 < K; k0 += 16) {
    const float4 xv = *(const float4*)(Xp + k0);
    const float4 wv = *(const float4*)(Wp + k0);
    Xs[lkk + 0][lrow] = xv.x; Xs[lkk + 1][lrow] = xv.y;
    Xs[lkk + 2][lrow] = xv.z; Xs[lkk + 3][lrow] = xv.w;
    Ws[lkk + 0][lrow] = wv.x; Ws[lkk + 1][lrow] = wv.y;
    Ws[lkk + 2][lrow] = wv.z; Ws[lkk + 3][lrow] = wv.w;
    __syncthreads();
#pragma unroll
    for (int kk = 0; kk < 16; ++kk) {
      const float4 a4 = *(const float4*)&Xs[kk][tm];
      const float4 b4 = *(const float4*)&Ws[kk][tn];
      const float av[4] = {a4.x, a4.y, a4.z, a4.w};
      const float bv[4] = {b4.x, b4.y, b4.z, b4.w};
#pragma unroll
      for (int i = 0; i < 4; ++i)
#pragma unroll
        for (int j = 0; j < 4; ++j) acc[i][j] += av[i] * bv[j];
    }
    __syncthreads();
  }
  float bvv[4] = {0.f, 0.f, 0.f, 0.f};
  if (bias) {
#pragma unroll
    for (int j = 0; j < 4; ++j) bvv[j] = bias[n0 + tn + j];
  }
#pragma unroll
  for (int i = 0; i < 4; ++i)
#pragma unroll
    for (int j = 0; j < 4; ++j)
      C[(size_t)(m0 + tm + i) * ldc + c0 + n0 + tn + j] = acc[i][j] + bvv[j];
}

// ------------------------- persistent LSTM scan (parity-tag poll) -----------
// Grid (32, BG): blockIdx.x = dir*16 + unit-slice w (32 units, 8 waves x 4).
// blockIdx.y = batch group (NT 16-row tiles). Per-dir 3-slab rotation:
// h(t) -> slab t%3 with bf16-LSB tag (t/3)&1; slab reuse (every 3 steps)
// flips the tag, so no clears are needed. Consumer polls slab (t+2)%3 until
// every ushort's LSB == ((t-1)/3)&1 — the successful poll IS the data.
// Skew <=1 (each step gates on ALL producers of t-1) => 3 slabs safe.
// One-time pre-clear (LSB=1) + entry ctr barrier vs cross-launch staleness.
// Per step: C{poll->hR} B1 D{MFMA+state->hS(tagged)} B2 E{preS<-pv;
// h stores fire-and-forget; out stores}. Raw s_barrier + lgkmcnt(0) only.
template <int NT>
__global__ __launch_bounds__(512, 2) void lstm_seq_kernel(
    const float* __restrict__ pre,           // [Bn][T][4096]
    const unsigned short* __restrict__ whh,  // bf16 [2 dirs][2048][512]
    unsigned short* __restrict__ hbuf,       // bf16 [2 dirs][3 slabs][640][512]
    float* __restrict__ out,                 // [Bn][T][1024]
    int T, unsigned* __restrict__ bar, unsigned base)
{
  __shared__ float preS[NT][4][16][34];      // [nt][gate][n][unit+pad]
  __shared__ float Tr[8][4][4][20];          // [wave][gate][du+pad][n]
  __shared__ unsigned short hS[NT * 16][36]; // [n_local][unit+pad] (write stg)
  __shared__ unsigned short hR[NT * 16][528];// [n_local][unit] (1056B stride)
  const int tid = threadIdx.x;               // 0..511
  const int v = tid >> 6;                    // wave 0..7
  const int l = tid & 63;
  const int d = blockIdx.x >> 4;
  const int w = blockIdx.x & 15;             // slice: units w*32..+31
  const int bg = blockIdx.y;
  const int fr = l & 15;
  const int fq = l >> 4;
  const int ubase = w * 32;
  const int unit = ubase + v * 4 + fq;
  const int nbase = bg * (NT * 16);
  const size_t SLOT = (size_t)640 * 512;
  unsigned* ctr = bar + (d * 8 + bg) * 16;   // 64B-spaced counters
  unsigned short* sl = hbuf + (size_t)d * 3 * SLOT;  // this dir's 3 slabs

  // A-frags: MFMA A row m=fr -> whh row (m>>2)*512 + ubase + v*4 + (m&3)
  s16x8 afr[16];
  {
    const unsigned short* arow = whh + (size_t)d * 2048 * 512 +
        ((size_t)(fr >> 2) * 512 + ubase + v * 4 + (fr & 3)) * 512 + fq * 8;
#pragma unroll
    for (int kk = 0; kk < 16; ++kk)
      afr[kk] = *(const s16x8*)(arow + kk * 32);
  }

  float creg[NT];
#pragma unroll
  for (int i = 0; i < NT; ++i) creg[i] = 0.f;

  // staging thread mapping: one float4 per thread per nt
  const int sc = tid & 7;
  const int sn = (tid >> 3) & 15;
  const int sg = tid >> 7;

  // ---- prologue: pre-clear own stripe in all 3 slabs with LSB=1 ----
  // (first tags used are (t/3)&1 = 0 for t=0,1,2 -> LSB=1 can't false-match)
  // stripe row = 8 ulongs of a 128-ulong (1024B) slab row.
  for (int s = 0; s < 3; ++s) {
    ulong_t* cb = (ulong_t*)(sl + (size_t)s * SLOT + (size_t)nbase * 512 + ubase);
    for (int i = tid; i < NT * 16 * 8; i += 512)
      __hip_atomic_store(cb + (size_t)(i >> 3) * 128 + (i & 7), LSBM,
                         __ATOMIC_RELAXED, __HIP_MEMORY_SCOPE_AGENT);
  }
  // ---- prologue: stage pre for t=0 ----
  {
    const int tt0 = d ? (T - 1) : 0;
#pragma unroll
    for (int nt = 0; nt < NT; ++nt) {
      const int n = nbase + nt * 16 + sn;
      const float4 pv = *(const float4*)(
          pre + ((size_t)n * T + tt0) * 4096 + d * 2048 + sg * 512 + ubase +
          sc * 4);
      *(float4*)&preS[nt][sg][sn][sc * 4] = pv;
    }
  }
  __syncthreads();  // drains pre-clears (vmcnt0 per wave) + preS lgkm
  // ---- launch-entry barrier: all 16 WGs of (d,bg) pre-cleared ----
  if (tid == 0) {
    __hip_atomic_fetch_add(ctr, 1u, __ATOMIC_RELAXED,
                           __HIP_MEMORY_SCOPE_AGENT);
    const unsigned target = base + 16u;
    long spins = 0;
    while (__hip_atomic_load(ctr, __ATOMIC_RELAXED,
                             __HIP_MEMORY_SCOPE_AGENT) < target) {
      __builtin_amdgcn_s_sleep(1);
      if (++spins > 2000000L) break;  // safety valve
    }
  }
  __syncthreads();

  float hnreg[NT];
  for (int t = 0; t < T; ++t) {
    const int tt = d ? (T - 1 - t) : t;
    const unsigned wtag = (unsigned)((t / 3) & 1);        // tag for h(t)
    unsigned short* wr = sl + (size_t)(t % 3) * SLOT;     // h(t) slab

    // ---- C: poll h(t-1) until every bf16 LSB matches rtag ----
    if (t > 0) {
      const unsigned rtag = (unsigned)(((t - 1) / 3) & 1);
      const ulong_t want = rtag ? LSBM : 0ull;
      const ulong_t* hq =
          (const ulong_t*)(sl + (size_t)((t + 2) % 3) * SLOT) +
          (size_t)nbase * 128;
      ulong_t u[4 * NT];
      bool ok = false;
      int it = 0;
      while (!ok && it < 200000) {
#pragma unroll
        for (int i = 0; i < 2 * NT; ++i) {
          const int cid = i * 512 + tid;                 // 16B chunk id
          const ulong_t* p = hq + (size_t)(cid >> 6) * 128 + (cid & 63) * 2;
          u[2 * i] = __hip_atomic_load(p, __ATOMIC_RELAXED,
                                       __HIP_MEMORY_SCOPE_AGENT);
          u[2 * i + 1] = __hip_atomic_load(p + 1, __ATOMIC_RELAXED,
                                           __HIP_MEMORY_SCOPE_AGENT);
        }
        bool bad = false;
#pragma unroll
        for (int i = 0; i < 4 * NT; ++i) bad |= ((u[i] & LSBM) != want);
        ok = !bad;
        ++it;
        if (!ok && it > 12) __builtin_amdgcn_s_sleep(1);
      }
#pragma unroll
      for (int i = 0; i < 2 * NT; ++i) {
        const int cid = i * 512 + tid;
        ulong_t* dst = (ulong_t*)&hR[cid >> 6][(cid & 63) * 8];
        dst[0] = u[2 * i];
        dst[1] = u[2 * i + 1];
      }
    }
    // ---- pv prefetch: pre(t+1) into registers ----
    float4 pv[NT];
    if (t + 1 < T) {
      const int ttn = d ? (T - 2 - t) : (t + 1);
#pragma unroll
      for (int nt = 0; nt < NT; ++nt) {
        const int n = nbase + nt * 16 + sn;
        pv[nt] = *(const float4*)(
            pre + ((size_t)n * T + ttn) * 4096 + d * 2048 + sg * 512 + ubase +
            sc * 4);
      }
    }
    // ---- B1: hR (and E(t-1)'s preS writes) visible to all waves ----
    asm volatile("s_waitcnt lgkmcnt(0)" ::: "memory");
    __builtin_amdgcn_s_barrier();
    __builtin_amdgcn_sched_barrier(0);

    // ---- D: gates + state update ----
#pragma unroll
    for (int nt = 0; nt < NT; ++nt) {
      f32x4 acc = (f32x4){0.f, 0.f, 0.f, 0.f};
      if (t > 0) {
        const unsigned short* bRd = &hR[nt * 16 + fr][fq * 8];
#pragma unroll
        for (int kk = 0; kk < 16; ++kk) {
          const s16x8 bv = *(const s16x8*)(bRd + kk * 32);
          acc = __builtin_amdgcn_mfma_f32_16x16x32_bf16(afr[kk], bv, acc,
                                                        0, 0, 0);
        }
      }
      // wave-local transpose (C row fq*4+r -> gate fq, du r; col fr -> n)
#pragma unroll
      for (int r = 0; r < 4; ++r) Tr[v][fq][r][fr] = acc[r];
      const int uu = v * 4 + fq;
      const float gi = Tr[v][0][fq][fr] + preS[nt][0][fr][uu];
      const float gf = Tr[v][1][fq][fr] + preS[nt][1][fr][uu];
      const float gg = Tr[v][2][fq][fr] + preS[nt][2][fr][uu];
      const float go = Tr[v][3][fq][fr] + preS[nt][3][fr][uu];
      const float cn = sigm(gf) * creg[nt] + sigm(gi) * tanh_f(gg);
      const float hn = sigm(go) * tanh_f(cn);
      creg[nt] = cn;
      hnreg[nt] = hn;
      hS[nt * 16 + fr][uu] =
          (unsigned short)((f2b_one(hn) & 0xFFFEu) | wtag);
      const int n0i = nbase + nt * 16 + fr;
      (void)n0i;
    }
    // ---- B2: hS ready; preS fully consumed; hR consumed ----
    asm volatile("s_waitcnt lgkmcnt(0)" ::: "memory");
    __builtin_amdgcn_s_barrier();
    __builtin_amdgcn_sched_barrier(0);

    // ---- E: preS <- pv; h stores fire-and-forget; out stores ----
    if (t + 1 < T) {
#pragma unroll
      for (int nt = 0; nt < NT; ++nt)
        *(float4*)&preS[nt][sg][sn][sc * 4] = pv[nt];
    }
    {
      const int un = tid & 7;       // ulong within 32-unit slice
      const int nl = tid >> 3;      // 0..63
      for (int p = nl; p < NT * 16; p += 64) {
        const ulong_t val = *(const ulong_t*)&hS[p][un * 4];
        __hip_atomic_store(
            (ulong_t*)(wr + (size_t)(nbase + p) * 512 + ubase) + un, val,
            __ATOMIC_RELAXED, __HIP_MEMORY_SCOPE_AGENT);
      }
    }
#pragma unroll
    for (int nt = 0; nt < NT; ++nt) {
      const int n = nbase + nt * 16 + fr;
      out[((size_t)n * T + tt) * 1024 + d * 512 + unit] = hnreg[nt];
    }
  }
}

// ------------------------- column attention pool ----------------------------
__global__ __launch_bounds__(256) void colpool_kernel(
    const float* __restrict__ cenc, const float* __restrict__ caw,
    const float* __restrict__ cab, const float* __restrict__ cmask,
    float* __restrict__ colh)
{
  __shared__ float part[8][33];
  __shared__ float wbuf[8];
  const int p = blockIdx.x;
  const int t = threadIdx.x >> 5;
  const int ln = threadIdx.x & 31;
  const float* row = cenc + ((size_t)p * 8 + t) * 1024;
  float s = 0.f;
  for (int j = ln; j < 1024; j += 32) s += row[j] * caw[j];
  part[t][ln] = s;
  __syncthreads();
  if (threadIdx.x < 8) {
    float lg = 0.f;
    for (int i = 0; i < 32; ++i) lg += part[threadIdx.x][i];
    lg += cab[0];
    wbuf[threadIdx.x] = (cmask[p * 8 + threadIdx.x] > 0.f) ? lg : -INFINITY;
  }
  __syncthreads();
  if (threadIdx.x == 0) {
    float mx = -INFINITY;
    for (int i = 0; i < 8; ++i) mx = fmaxf(mx, wbuf[i]);
    float e[8];
    float sum = 0.f;
    for (int i = 0; i < 8; ++i) { e[i] = expf(wbuf[i] - mx); sum += e[i]; }
    for (int i = 0; i < 8; ++i) wbuf[i] = e[i] / sum;
  }
  __syncthreads();
  for (int h = threadIdx.x; h < 1024; h += 256) {
    float a = 0.f;
#pragma unroll
    for (int i = 0; i < 8; ++i) a += wbuf[i] * cenc[((size_t)p * 8 + i) * 1024 + h];
    colh[(size_t)p * 1024 + h] = a;
  }
}

// ------------------------- gather observed ----------------------------------
__global__ __launch_bounds__(256) void gather_kernel(
    const float* __restrict__ colh, const int* __restrict__ gold_num,
    const int* __restrict__ gold_cols, const int* __restrict__ ncol,
    float* __restrict__ obs)
{
  const int idx = blockIdx.x * 256 + threadIdx.x;
  const int h = idx & 1023;
  const int k = (idx >> 10) & 3;
  const int b = idx >> 12;
  int gn = gold_num[b];
  if (gn > 4) gn = 4;
  const float m = (k < gn) ? 1.f : 0.f;
  const int col = gold_cols[b * 4 + k];
  const int NC = ncol[0];
  obs[idx] = m * colh[(size_t)(b * NC + col) * 1024 + h];
}

// ------------------------- fused attention (per b,k) ------------------------
__global__ __launch_bounds__(128) void attn_kernel(
    const float* __restrict__ akey, const float* __restrict__ qenc,
    const float* __restrict__ qmask, float* __restrict__ qhid)
{
  __shared__ float ak[1024];
  __shared__ float red[128];
  __shared__ float at[128];
  const int bk = blockIdx.x;
  const int b = bk >> 2;
  const int tid = threadIdx.x;
  for (int i = tid; i < 1024; i += 128) ak[i] = akey[(size_t)bk * 1024 + i];
  __syncthreads();
  const float* qrow = qenc + ((size_t)b * 128 + tid) * 1024;
  float s = 0.f;
  for (int hh = 0; hh < 1024; hh += 4) {
    const float4 qv = *(const float4*)(qrow + hh);
    s += ak[hh] * qv.x + ak[hh + 1] * qv.y + ak[hh + 2] * qv.z + ak[hh + 3] * qv.w;
  }
  s = (qmask[b * 128 + tid] > 0.f) ? s : -INFINITY;
  at[tid] = s;
  red[tid] = s;
  __syncthreads();
  for (int off = 64; off > 0; off >>= 1) {
    if (tid < off) red[tid] = fmaxf(red[tid], red[tid + off]);
    __syncthreads();
  }
  const float mx = red[0];
  __syncthreads();
  const float e = expf(at[tid] - mx);
  red[tid] = e;
  __syncthreads();
  for (int off = 64; off > 0; off >>= 1) {
    if (tid < off) red[tid] += red[tid + off];
    __syncthreads();
  }
  const float inv = 1.f / red[0];
  __syncthreads();
  at[tid] = e * inv;
  __syncthreads();
  for (int h = tid; h < 1024; h += 128) {
    float a = 0.f;
    for (int q = 0; q < 128; ++q)
      a += at[q] * qenc[((size_t)b * 128 + q) * 1024 + h];
    qhid[(size_t)bk * 1024 + h] = a;
  }
}

// ------------------------- final epilogue -----------------------------------
__global__ __launch_bounds__(64) void final_kernel(
    const float* __restrict__ A, const float* __restrict__ Bm,
    const float* __restrict__ w2, const float* __restrict__ b2,
    const int* __restrict__ gold_num, const float* __restrict__ qmask,
    float* __restrict__ out)
{
  const int bkq = blockIdx.x;
  const int q = bkq & 127;
  const int k = (bkq >> 7) & 3;
  const int b = bkq >> 9;
  int gn = gold_num[b];
  if (gn > 4) gn = 4;
  const bool act = (k < gn) && (qmask[b * 128 + q] > 0.f);
  const int lane = threadIdx.x;
  const int obase = (b * 4 + k) * 128 + q;
  if (!act) {
    if (lane == 0) {
      out[obase] = -1e30f;          // finite sentinel (ref has -inf; see r1)
      out[16384 + obase] = -1e30f;
    }
    return;
  }
  const float* Ar = A + ((size_t)b * 128 + q) * 1024;
  const float* Br = Bm + (size_t)(b * 4 + k) * 1024;
  float s0 = 0.f, s1 = 0.f;
  for (int o = lane; o < 1024; o += 64) {
    const float v = tanhf(Ar[o] + Br[o]);
    s0 += v * w2[o];
    s1 += v * w2[1024 + o];
  }
#pragma unroll
  for (int off = 32; off > 0; off >>= 1) {
    s0 += __shfl_down(s0, off, 64);
    s1 += __shfl_down(s1, off, 64);
  }
  if (lane == 0) {
    out[obase] = s0 + b2[0];
    out[16384 + obase] = s1 + b2[1];
  }
}

// ---------------------------------------------------------------------------
extern "C" void kernel_launch(void* const* d_in, const int* in_sizes, int n_in,
                              void* d_out, int out_size, void* d_ws, size_t ws_size,
                              hipStream_t stream)
{
  const float* qe      = (const float*)d_in[0];
  const float* pce     = (const float*)d_in[1];
  const int* gold_num  = (const int*)d_in[2];
  const int* gold_cols = (const int*)d_in[3];
  const int* ncol      = (const int*)d_in[5];
  const float* q_Wih   = (const float*)d_in[6];
  const float* q_Whh   = (const float*)d_in[7];
  const float* q_b     = (const float*)d_in[8];
  const float* c_Wih   = (const float*)d_in[9];
  const float* c_Whh   = (const float*)d_in[10];
  const float* c_b     = (const float*)d_in[11];
  const float* caw     = (const float*)d_in[12];
  const float* cab     = (const float*)d_in[13];
  const float* obaW    = (const float*)d_in[14];
  const float* obab    = (const float*)d_in[15];
  const float* obcW    = (const float*)d_in[16];
  const float* obcb    = (const float*)d_in[17];
  const float* qpW     = (const float*)d_in[18];
  const float* qpb     = (const float*)d_in[19];
  const float* o1W     = (const float*)d_in[20];
  const float* o1b     = (const float*)d_in[21];
  const float* o2W     = (const float*)d_in[22];
  const float* o2b     = (const float*)d_in[23];
  float* outp = (float*)d_out;

  float* ws = (float*)d_ws;
  size_t off = 0;
  float* pre  = ws + off; off += 640UL * 8 * 4096;   // also reused as A matrix
  float* bufA = ws + off; off += 640UL * 8 * 1024;
  float* bufB = ws + off; off += 640UL * 8 * 1024;
  float* colh = ws + off; off += 640UL * 1024;
  float* qmask = ws + off; off += 4096;
  float* cmask = ws + off; off += 5120;
  float* obs  = ws + off; off += 131072;
  float* akey = ws + off; off += 131072;
  float* qhid = ws + off; off += 131072;
  float* vec  = ws + off; off += 262144;
  float* Bm   = ws + off; off += 131072;
  unsigned short* xb = (unsigned short*)(ws + off); off += 2621440;  // bf16 acts
  unsigned short* wb = (unsigned short*)(ws + off); off += 2097152;  // bf16 Wih
  unsigned short* whhq = (unsigned short*)(ws + off); off += 2097152; // q_Whh bf16
  unsigned short* whhc = (unsigned short*)(ws + off); off += 2097152; // c_Whh bf16
  unsigned short* hbuf = (unsigned short*)(ws + off); off += 983040;  // 2 dirs x 3 slabs
  unsigned* bar = (unsigned*)(ws + off); off += 256;  // 16 counters x 64B
  float* Amat = pre;

  const dim3 blk(256);
  auto cvt = [&](const float* src, unsigned short* dst, int n) {
    hipLaunchKernelGGL(f2b_kernel, dim3((n / 4 + 255) / 256), blk, 0, stream,
                       src, dst, n / 4);
  };

  // counters must start at 0 every call (ws is poisoned 0xAA)
  hipMemsetAsync(bar, 0, 1024, stream);

  hipLaunchKernelGGL(mask_kernel, dim3(2304), blk, 0, stream, qe, pce, qmask, cmask);

  // recurrent weights -> bf16 (once)
  cvt(q_Whh, whhq, 4194304);
  cvt(c_Whh, whhc, 4194304);

  // ---- column biLSTM (B=640, T=8): grid (32,8), NT=5 ----
  // entry counters (d*8+bg): +16 per launch
  for (int l = 0; l < 2; ++l) {
    const float* xin = (l == 0) ? pce : bufA;
    float* enc = (l == 0) ? bufA : bufB;
    cvt(xin, xb, 5242880);
    cvt(c_Wih + (size_t)l * 4194304, wb, 4194304);
    hipLaunchKernelGGL(mfma_gemm_kernel, dim3(4096 / 128, 5120 / 128), blk, 0,
                       stream, xb, wb, c_b + l * 4096, pre,
                       1024, 1024, 1024, 0, 4096, 0);
    hipLaunchKernelGGL((lstm_seq_kernel<5>), dim3(32, 8), dim3(512), 0, stream,
                       pre, whhc + (size_t)l * 2 * 2048 * 512, hbuf, enc,
                       8, bar, (unsigned)(l * 16));
  }
  hipLaunchKernelGGL(colpool_kernel, dim3(640), blk, 0, stream,
                     bufB, caw, cab, cmask, colh);
  hipLaunchKernelGGL(gather_kernel, dim3(512), blk, 0, stream,
                     colh, gold_num, gold_cols, ncol, obs);

  // ---- question biLSTM (B=32, T=128): grid (32,1), NT=2 ----
  // entry counters (d,0): at 32 after col launches; +16 per q launch
  for (int l = 0; l < 2; ++l) {
    const float* xin = (l == 0) ? qe : bufA;
    float* enc = (l == 0) ? bufA : bufB;
    cvt(xin, xb, 4194304);
    cvt(q_Wih + (size_t)l * 4194304, wb, 4194304);
    hipLaunchKernelGGL(mfma_gemm_kernel, dim3(4096 / 128, 4096 / 128), blk, 0,
                       stream, xb, wb, q_b + l * 4096, pre,
                       1024, 1024, 1024, 0, 4096, 0);
    hipLaunchKernelGGL((lstm_seq_kernel<2>), dim3(32, 1), dim3(512), 0, stream,
                       pre, whhq + (size_t)l * 2 * 2048 * 512, hbuf, enc,
                       128, bar, (unsigned)(32 + l * 16));
  }
  const float* qenc = bufB;

  // att_key = observed @ ob_attn_W^T + b   (small, fp32 path)
  hipLaunchKernelGGL(gemm_kernel, dim3(16, 2), blk, 0, stream,
                     obs, obaW, obab, akey, 128, 1024, 1024, 1024, 1024, 0, 1024, 0);
  hipLaunchKernelGGL(attn_kernel, dim3(128), dim3(128), 0, stream,
                     akey, qenc, qmask, qhid);
  hipLaunchKernelGGL(gemm_kernel, dim3(16, 2), blk, 0, stream,
                     obs, obcW, obcb, vec, 128, 1024, 1024, 1024, 1024, 0, 2048, 0);
  hipLaunchKernelGGL(gemm_kernel, dim3(16, 2), blk, 0, stream,
                     qhid, qpW, qpb, vec, 128, 1024, 1024, 1024, 1024, 0, 2048, 1024);
  // A = qenc @ out1_W[:, :1024]^T + b1  (bf16 MFMA)
  cvt(qenc, xb, 4194304);
  cvt(o1W, wb, 3145728);
  hipLaunchKernelGGL(mfma_gemm_kernel, dim3(1024 / 128, 4096 / 128), blk, 0,
                     stream, xb, wb, o1b, Amat, 1024, 1024, 3072, 0, 1024, 0);
  // Bm = vec @ out1_W[:, 1024:]^T (fp32 path)
  hipLaunchKernelGGL(gemm_kernel, dim3(16, 2), blk, 0, stream,
                     vec, o1W, nullptr, Bm, 128, 1024, 2048, 2048, 3072, 1024, 1024, 0);
  hipLaunchKernelGGL(final_kernel, dim3(16384), dim3(64), 0, stream,
                     Amat, Bm, o2W, o2b, gold_num, qmask, outp);
}

// Round 6
// 1968.978 us; speedup vs baseline: 1.0982x; 1.0035x over previous
//
#include <hip/hip_runtime.h>
#include <math.h>

// ---------------------------------------------------------------------------
// WhereValuePredictor on MI355X — round 11: exchange-chain trim.
// r10 post-mortem: parity-tag poll passed, 489->439us/launch, step 3.43us
// (vs ~2us 2-hop floor). Residual chain: h stored late (in E, after B2 +
// preS writes) and consumer's first poll read only issues at C (~900cy).
// This round, on the passing r10 protocol (3 slabs/dir, bf16-LSB tag
// (t/3)&1, no clears):
//  - hS removed; tagged h stored DIRECTLY in D right after the state
//    update, packed to 4B via __shfl_xor(.,16) (32-bit agent atomics).
//  - E issues next step's poll loads into carried registers; C checks the
//    prefetched values first (free detect when data already arrived).
//  - __launch_bounds__(512) (grids never exceed 1 WG/CU; frees VGPRs).
//  - __expf-based tanh/exp in final/attn/colpool.
// ---------------------------------------------------------------------------

using f32x4 = __attribute__((ext_vector_type(4))) float;
using s16x8 = __attribute__((ext_vector_type(8))) short;
typedef unsigned long long ulong_t;

#define ASYNC_COPY16(gsrc, ldst)                                               \
  __builtin_amdgcn_global_load_lds(                                            \
      (const __attribute__((address_space(1))) void*)(gsrc),                   \
      (__attribute__((address_space(3))) void*)(ldst), 16, 0, 0)

#define LSBM 0x0001000100010001ull

static __device__ __forceinline__ float sigm(float x) {
  return __builtin_amdgcn_rcpf(1.0f + __expf(-x));
}
static __device__ __forceinline__ float tanh_f(float x) {
  return 1.0f - 2.0f * __builtin_amdgcn_rcpf(__expf(2.0f * x) + 1.0f);
}

static __device__ __forceinline__ unsigned short f2b_one(float x) {
  unsigned int u = __float_as_uint(x);
  u = (u + 0x7FFFu + ((u >> 16) & 1u)) >> 16;  // RNE
  return (unsigned short)u;
}

// ------------------------- fp32 -> bf16 convert ----------------------------
__global__ __launch_bounds__(256) void f2b_kernel(
    const float* __restrict__ in, unsigned short* __restrict__ out, int n4)
{
  const int i = blockIdx.x * 256 + threadIdx.x;
  if (i >= n4) return;
  const float4 v = ((const float4*)in)[i];
  ushort4 r;
  r.x = f2b_one(v.x); r.y = f2b_one(v.y);
  r.z = f2b_one(v.z); r.w = f2b_one(v.w);
  ((ushort4*)out)[i] = r;
}

// ------------------------- masks -------------------------------------------
__global__ __launch_bounds__(256) void mask_kernel(
    const float* __restrict__ qe, const float* __restrict__ pce,
    float* __restrict__ qmask, float* __restrict__ cmask)
{
  const int w = threadIdx.x >> 6;
  const int lane = threadIdx.x & 63;
  const int row = blockIdx.x * 4 + w;  // 0..9215
  const float* src = (row < 4096) ? (qe + (size_t)row * 1024)
                                  : (pce + (size_t)(row - 4096) * 1024);
  float s = 0.f;
#pragma unroll
  for (int j = 0; j < 16; ++j) s += fabsf(src[lane + j * 64]);
#pragma unroll
  for (int off = 32; off > 0; off >>= 1) s += __shfl_down(s, off, 64);
  if (lane == 0) {
    const float m = (s != 0.f) ? 1.f : 0.f;
    if (row < 4096) qmask[row] = m;
    else cmask[row - 4096] = m;
  }
}

// ------------------------- bf16 MFMA GEMM (m97-style) ----------------------
__global__ __launch_bounds__(256) void mfma_gemm_kernel(
    const unsigned short* __restrict__ X, const unsigned short* __restrict__ W,
    const float* __restrict__ bias, float* __restrict__ C,
    int K, int ldx, int ldw, int k0w, int ldc, int c0)
{
  __shared__ unsigned short As[128 * 32];
  __shared__ unsigned short Bs[128 * 32];
  const int tid = threadIdx.x;
  const int w = tid >> 6;
  const int l = tid & 63;
  const int m0 = blockIdx.y * 128;
  const int n0 = blockIdx.x * 128;
  const int wm = (w >> 1) * 64;
  const int wn = (w & 1) * 64;

  const unsigned short* xg =
      X + (size_t)(m0 + w * 32 + (l >> 2)) * ldx + (l & 3) * 8;
  const unsigned short* wgp =
      W + (size_t)(n0 + w * 32 + (l >> 2)) * ldw + k0w + (l & 3) * 8;
  unsigned short* asb = As + w * 1024;
  unsigned short* bsb = Bs + w * 1024;

  const int fr = l & 15;
  const int fq = l >> 4;
  const unsigned short* aRd = As + (wm + fr) * 32 + fq * 8;
  const unsigned short* bRd = Bs + (wn + fr) * 32 + fq * 8;

  f32x4 acc[4][4];
#pragma unroll
  for (int i = 0; i < 4; ++i)
#pragma unroll
    for (int j = 0; j < 4; ++j) acc[i][j] = (f32x4){0.f, 0.f, 0.f, 0.f};

  for (int k0 = 0; k0 < K; k0 += 32) {
    ASYNC_COPY16(xg + k0, asb);
    ASYNC_COPY16(xg + (size_t)16 * ldx + k0, asb + 512);
    ASYNC_COPY16(wgp + k0, bsb);
    ASYNC_COPY16(wgp + (size_t)16 * ldw + k0, bsb + 512);
    __syncthreads();
    s16x8 a[4], b[4];
#pragma unroll
    for (int i = 0; i < 4; ++i) a[i] = *(const s16x8*)(aRd + i * 512);
#pragma unroll
    for (int j = 0; j < 4; ++j) b[j] = *(const s16x8*)(bRd + j * 512);
#pragma unroll
    for (int i = 0; i < 4; ++i)
#pragma unroll
      for (int j = 0; j < 4; ++j)
        acc[i][j] = __builtin_amdgcn_mfma_f32_16x16x32_bf16(
            a[i], b[j], acc[i][j], 0, 0, 0);
    __syncthreads();
  }

#pragma unroll
  for (int j = 0; j < 4; ++j) {
    const int col = n0 + wn + j * 16 + fr;
    const float bj = bias ? bias[col] : 0.f;
#pragma unroll
    for (int i = 0; i < 4; ++i) {
      const int row = m0 + wm + i * 16 + fq * 4;
#pragma unroll
      for (int r = 0; r < 4; ++r)
        C[(size_t)(row + r) * ldc + c0 + col] = acc[i][j][r] + bj;
    }
  }
}

// ------------------------- generic fp32 GEMM (small tails) ------------------
__global__ __launch_bounds__(256) void gemm_kernel(
    const float* __restrict__ X, const float* __restrict__ W,
    const float* __restrict__ bias, float* __restrict__ C,
    int M, int N, int K, int ldx, int ldw, int k0w, int ldc, int c0)
{
  __shared__ float Xs[16][68];
  __shared__ float Ws[16][68];
  const int tid = threadIdx.x;
  const int m0 = blockIdx.y * 64;
  const int n0 = blockIdx.x * 64;
  const int lrow = tid >> 2;
  const int lkk = (tid & 3) << 2;
  const float* Xp = X + (size_t)(m0 + lrow) * ldx + lkk;
  const float* Wp = W + (size_t)(n0 + lrow) * ldw + k0w + lkk;
  const int tm = (tid >> 4) << 2;
  const int tn = (tid & 15) << 2;
  float acc[4][4];
#pragma unroll
  for (int i = 0; i < 4; ++i)
#pragma unroll
    for (int j = 0; j < 4; ++j) acc[i][j] = 0.f;

  for (int k0 = 0; k0 < K; k0 += 16) {
    const float4 xv = *(const float4*)(Xp + k0);
    const float4 wv = *(const float4*)(Wp + k0);
    Xs[lkk + 0][lrow] = xv.x; Xs[lkk + 1][lrow] = xv.y;
    Xs[lkk + 2][lrow] = xv.z; Xs[lkk + 3][lrow] = xv.w;
    Ws[lkk + 0][lrow] = wv.x; Ws[lkk + 1][lrow] = wv.y;
    Ws[lkk + 2][lrow] = wv.z; Ws[lkk + 3][lrow] = wv.w;
    __syncthreads();
#pragma unroll
    for (int kk = 0; kk < 16; ++kk) {
      const float4 a4 = *(const float4*)&Xs[kk][tm];
      const float4 b4 = *(const float4*)&Ws[kk][tn];
      const float av[4] = {a4.x, a4.y, a4.z, a4.w};
      const float bv[4] = {b4.x, b4.y, b4.z, b4.w};
#pragma unroll
      for (int i = 0; i < 4; ++i)
#pragma unroll
        for (int j = 0; j < 4; ++j) acc[i][j] += av[i] * bv[j];
    }
    __syncthreads();
  }
  float bvv[4] = {0.f, 0.f, 0.f, 0.f};
  if (bias) {
#pragma unroll
    for (int j = 0; j < 4; ++j) bvv[j] = bias[n0 + tn + j];
  }
#pragma unroll
  for (int i = 0; i < 4; ++i)
#pragma unroll
    for (int j = 0; j < 4; ++j)
      C[(size_t)(m0 + tm + i) * ldc + c0 + n0 + tn + j] = acc[i][j] + bvv[j];
}

// ------------------------- persistent LSTM scan (parity-tag poll) -----------
// Grid (32, BG): blockIdx.x = dir*16 + unit-slice w. blockIdx.y = batch
// group. 3 slabs/dir; h(t) -> slab t%3 with bf16-LSB tag (t/3)&1 (no
// clears; slab reuse flips tag). Consumer polls slab (t+2)%3 for tag
// ((t-1)/3)&1 — successful poll IS the data. Early direct h stores in D
// (packed 4B via shfl_xor); poll loads prefetched in E, checked at C.
// Per step: C{check/retry -> hR; pv loads} B1 D{MFMA+state; h+out stores}
// B2 E{preS<-pv; prefetch next poll}. Raw s_barrier + lgkmcnt(0) only.
template <int NT>
__global__ __launch_bounds__(512) void lstm_seq_kernel(
    const float* __restrict__ pre,           // [Bn][T][4096]
    const unsigned short* __restrict__ whh,  // bf16 [2 dirs][2048][512]
    unsigned short* __restrict__ hbuf,       // bf16 [2 dirs][3 slabs][640][512]
    float* __restrict__ out,                 // [Bn][T][1024]
    int T, unsigned* __restrict__ bar, unsigned base)
{
  __shared__ float preS[NT][4][16][34];      // [nt][gate][n][unit+pad]
  __shared__ float Tr[8][4][4][20];          // [wave][gate][du+pad][n]
  __shared__ unsigned short hR[NT * 16][528];// [n_local][unit] (1056B stride)
  const int tid = threadIdx.x;               // 0..511
  const int v = tid >> 6;                    // wave 0..7
  const int l = tid & 63;
  const int d = blockIdx.x >> 4;
  const int w = blockIdx.x & 15;             // slice: units w*32..+31
  const int bg = blockIdx.y;
  const int fr = l & 15;
  const int fq = l >> 4;
  const int ubase = w * 32;
  const int unit = ubase + v * 4 + fq;
  const int nbase = bg * (NT * 16);
  const size_t SLOT = (size_t)640 * 512;
  unsigned* ctr = bar + (d * 8 + bg) * 16;   // 64B-spaced counters
  unsigned short* sl = hbuf + (size_t)d * 3 * SLOT;  // this dir's 3 slabs

  // A-frags: MFMA A row m=fr -> whh row (m>>2)*512 + ubase + v*4 + (m&3)
  s16x8 afr[16];
  {
    const unsigned short* arow = whh + (size_t)d * 2048 * 512 +
        ((size_t)(fr >> 2) * 512 + ubase + v * 4 + (fr & 3)) * 512 + fq * 8;
#pragma unroll
    for (int kk = 0; kk < 16; ++kk)
      afr[kk] = *(const s16x8*)(arow + kk * 32);
  }

  float creg[NT];
#pragma unroll
  for (int i = 0; i < NT; ++i) creg[i] = 0.f;

  // staging thread mapping: one float4 per thread per nt
  const int sc = tid & 7;
  const int sn = (tid >> 3) & 15;
  const int sg = tid >> 7;

  // ---- prologue: pre-clear own stripe in all 3 slabs with LSB=1 ----
  // (first tags used are (t/3)&1 = 0 for t=0,1,2 -> LSB=1 can't false-match)
  for (int s = 0; s < 3; ++s) {
    ulong_t* cb = (ulong_t*)(sl + (size_t)s * SLOT + (size_t)nbase * 512 + ubase);
    for (int i = tid; i < NT * 16 * 8; i += 512)
      __hip_atomic_store(cb + (size_t)(i >> 3) * 128 + (i & 7), LSBM,
                         __ATOMIC_RELAXED, __HIP_MEMORY_SCOPE_AGENT);
  }
  // ---- prologue: stage pre for t=0 ----
  {
    const int tt0 = d ? (T - 1) : 0;
#pragma unroll
    for (int nt = 0; nt < NT; ++nt) {
      const int n = nbase + nt * 16 + sn;
      const float4 pv = *(const float4*)(
          pre + ((size_t)n * T + tt0) * 4096 + d * 2048 + sg * 512 + ubase +
          sc * 4);
      *(float4*)&preS[nt][sg][sn][sc * 4] = pv;
    }
  }
  __syncthreads();  // drains pre-clears (vmcnt0 per wave) + preS lgkm
  // ---- launch-entry barrier: all 16 WGs of (d,bg) pre-cleared ----
  if (tid == 0) {
    __hip_atomic_fetch_add(ctr, 1u, __ATOMIC_RELAXED,
                           __HIP_MEMORY_SCOPE_AGENT);
    const unsigned target = base + 16u;
    long spins = 0;
    while (__hip_atomic_load(ctr, __ATOMIC_RELAXED,
                             __HIP_MEMORY_SCOPE_AGENT) < target) {
      __builtin_amdgcn_s_sleep(1);
      if (++spins > 2000000L) break;  // safety valve
    }
  }
  __syncthreads();

  ulong_t u[4 * NT];  // poll data, prefetched in E, checked/used in C
  for (int t = 0; t < T; ++t) {
    const int tt = d ? (T - 1 - t) : t;
    const unsigned wtag = (unsigned)((t / 3) & 1);        // tag for h(t)
    unsigned short* wr = sl + (size_t)(t % 3) * SLOT;     // h(t) slab

    // ---- C: validate prefetched h(t-1); retry-poll if stale; -> hR ----
    if (t > 0) {
      const unsigned rtag = (unsigned)(((t - 1) / 3) & 1);
      const ulong_t want = rtag ? LSBM : 0ull;
      const ulong_t* hq =
          (const ulong_t*)(sl + (size_t)((t + 2) % 3) * SLOT) +
          (size_t)nbase * 128;
      bool bad0 = false;
#pragma unroll
      for (int i = 0; i < 4 * NT; ++i) bad0 |= ((u[i] & LSBM) != want);
      if (bad0) {
        bool ok = false;
        int it = 0;
        while (!ok && it < 200000) {
#pragma unroll
          for (int i = 0; i < 2 * NT; ++i) {
            const int cid = i * 512 + tid;                 // 16B chunk id
            const ulong_t* p = hq + (size_t)(cid >> 6) * 128 + (cid & 63) * 2;
            u[2 * i] = __hip_atomic_load(p, __ATOMIC_RELAXED,
                                         __HIP_MEMORY_SCOPE_AGENT);
            u[2 * i + 1] = __hip_atomic_load(p + 1, __ATOMIC_RELAXED,
                                             __HIP_MEMORY_SCOPE_AGENT);
          }
          bool bad = false;
#pragma unroll
          for (int i = 0; i < 4 * NT; ++i) bad |= ((u[i] & LSBM) != want);
          ok = !bad;
          ++it;
          if (!ok && it > 8) __builtin_amdgcn_s_sleep(1);
        }
      }
#pragma unroll
      for (int i = 0; i < 2 * NT; ++i) {
        const int cid = i * 512 + tid;
        ulong_t* dst = (ulong_t*)&hR[cid >> 6][(cid & 63) * 8];
        dst[0] = u[2 * i];
        dst[1] = u[2 * i + 1];
      }
    }
    // ---- pv prefetch: pre(t+1) into registers ----
    float4 pv[NT];
    if (t + 1 < T) {
      const int ttn = d ? (T - 2 - t) : (t + 1);
#pragma unroll
      for (int nt = 0; nt < NT; ++nt) {
        const int n = nbase + nt * 16 + sn;
        pv[nt] = *(const float4*)(
            pre + ((size_t)n * T + ttn) * 4096 + d * 2048 + sg * 512 + ubase +
            sc * 4);
      }
    }
    // ---- B1: hR (and E(t-1)'s preS writes) visible to all waves ----
    asm volatile("s_waitcnt lgkmcnt(0)" ::: "memory");
    __builtin_amdgcn_s_barrier();
    __builtin_amdgcn_sched_barrier(0);

    // ---- D: gates + state update + EARLY tagged h stores + out stores ----
#pragma unroll
    for (int nt = 0; nt < NT; ++nt) {
      f32x4 acc = (f32x4){0.f, 0.f, 0.f, 0.f};
      if (t > 0) {
        const unsigned short* bRd = &hR[nt * 16 + fr][fq * 8];
#pragma unroll
        for (int kk = 0; kk < 16; ++kk) {
          const s16x8 bv = *(const s16x8*)(bRd + kk * 32);
          acc = __builtin_amdgcn_mfma_f32_16x16x32_bf16(afr[kk], bv, acc,
                                                        0, 0, 0);
        }
      }
      // wave-local transpose (C row fq*4+r -> gate fq, du r; col fr -> n)
#pragma unroll
      for (int r = 0; r < 4; ++r) Tr[v][fq][r][fr] = acc[r];
      const int uu = v * 4 + fq;
      const float gi = Tr[v][0][fq][fr] + preS[nt][0][fr][uu];
      const float gf = Tr[v][1][fq][fr] + preS[nt][1][fr][uu];
      const float gg = Tr[v][2][fq][fr] + preS[nt][2][fr][uu];
      const float go = Tr[v][3][fq][fr] + preS[nt][3][fr][uu];
      const float cn = sigm(gf) * creg[nt] + sigm(gi) * tanh_f(gg);
      const float hn = sigm(go) * tanh_f(cn);
      creg[nt] = cn;
      // early tagged h store: pack fq-pair (unit, unit+1) into 4B
      const unsigned hv =
          (unsigned)((f2b_one(hn) & 0xFFFEu) | wtag);
      const unsigned pv16 = (unsigned)__shfl_xor((int)hv, 16, 64);
      const int n = nbase + nt * 16 + fr;
      if ((fq & 1) == 0) {
        const unsigned pk = hv | (pv16 << 16);
        __hip_atomic_store(
            (unsigned*)(wr + (size_t)n * 512) + (unit >> 1), pk,
            __ATOMIC_RELAXED, __HIP_MEMORY_SCOPE_AGENT);
      }
      out[((size_t)n * T + tt) * 1024 + d * 512 + unit] = hn;
    }
    // ---- B2: preS consumed; hR consumed (rewritten at C(t+1)) ----
    asm volatile("s_waitcnt lgkmcnt(0)" ::: "memory");
    __builtin_amdgcn_s_barrier();
    __builtin_amdgcn_sched_barrier(0);

    // ---- E: preS <- pv; prefetch next step's poll loads ----
    if (t + 1 < T) {
#pragma unroll
      for (int nt = 0; nt < NT; ++nt)
        *(float4*)&preS[nt][sg][sn][sc * 4] = pv[nt];
      const ulong_t* hq =
          (const ulong_t*)(sl + (size_t)((t + 3) % 3) * SLOT) +
          (size_t)nbase * 128;
#pragma unroll
      for (int i = 0; i < 2 * NT; ++i) {
        const int cid = i * 512 + tid;
        const ulong_t* p = hq + (size_t)(cid >> 6) * 128 + (cid & 63) * 2;
        u[2 * i] = __hip_atomic_load(p, __ATOMIC_RELAXED,
                                     __HIP_MEMORY_SCOPE_AGENT);
        u[2 * i + 1] = __hip_atomic_load(p + 1, __ATOMIC_RELAXED,
                                         __HIP_MEMORY_SCOPE_AGENT);
      }
    }
  }
}

// ------------------------- column attention pool ----------------------------
__global__ __launch_bounds__(256) void colpool_kernel(
    const float* __restrict__ cenc, const float* __restrict__ caw,
    const float* __restrict__ cab, const float* __restrict__ cmask,
    float* __restrict__ colh)
{
  __shared__ float part[8][33];
  __shared__ float wbuf[8];
  const int p = blockIdx.x;
  const int t = threadIdx.x >> 5;
  const int ln = threadIdx.x & 31;
  const float* row = cenc + ((size_t)p * 8 + t) * 1024;
  float s = 0.f;
  for (int j = ln; j < 1024; j += 32) s += row[j] * caw[j];
  part[t][ln] = s;
  __syncthreads();
  if (threadIdx.x < 8) {
    float lg = 0.f;
    for (int i = 0; i < 32; ++i) lg += part[threadIdx.x][i];
    lg += cab[0];
    wbuf[threadIdx.x] = (cmask[p * 8 + threadIdx.x] > 0.f) ? lg : -INFINITY;
  }
  __syncthreads();
  if (threadIdx.x == 0) {
    float mx = -INFINITY;
    for (int i = 0; i < 8; ++i) mx = fmaxf(mx, wbuf[i]);
    float e[8];
    float sum = 0.f;
    for (int i = 0; i < 8; ++i) { e[i] = __expf(wbuf[i] - mx); sum += e[i]; }
    for (int i = 0; i < 8; ++i) wbuf[i] = e[i] / sum;
  }
  __syncthreads();
  for (int h = threadIdx.x; h < 1024; h += 256) {
    float a = 0.f;
#pragma unroll
    for (int i = 0; i < 8; ++i) a += wbuf[i] * cenc[((size_t)p * 8 + i) * 1024 + h];
    colh[(size_t)p * 1024 + h] = a;
  }
}

// ------------------------- gather observed ----------------------------------
__global__ __launch_bounds__(256) void gather_kernel(
    const float* __restrict__ colh, const int* __restrict__ gold_num,
    const int* __restrict__ gold_cols, const int* __restrict__ ncol,
    float* __restrict__ obs)
{
  const int idx = blockIdx.x * 256 + threadIdx.x;
  const int h = idx & 1023;
  const int k = (idx >> 10) & 3;
  const int b = idx >> 12;
  int gn = gold_num[b];
  if (gn > 4) gn = 4;
  const float m = (k < gn) ? 1.f : 0.f;
  const int col = gold_cols[b * 4 + k];
  const int NC = ncol[0];
  obs[idx] = m * colh[(size_t)(b * NC + col) * 1024 + h];
}

// ------------------------- fused attention (per b,k) ------------------------
__global__ __launch_bounds__(128) void attn_kernel(
    const float* __restrict__ akey, const float* __restrict__ qenc,
    const float* __restrict__ qmask, float* __restrict__ qhid)
{
  __shared__ float ak[1024];
  __shared__ float red[128];
  __shared__ float at[128];
  const int bk = blockIdx.x;
  const int b = bk >> 2;
  const int tid = threadIdx.x;
  for (int i = tid; i < 1024; i += 128) ak[i] = akey[(size_t)bk * 1024 + i];
  __syncthreads();
  const float* qrow = qenc + ((size_t)b * 128 + tid) * 1024;
  float s = 0.f;
  for (int hh = 0; hh < 1024; hh += 4) {
    const float4 qv = *(const float4*)(qrow + hh);
    s += ak[hh] * qv.x + ak[hh + 1] * qv.y + ak[hh + 2] * qv.z + ak[hh + 3] * qv.w;
  }
  s = (qmask[b * 128 + tid] > 0.f) ? s : -INFINITY;
  at[tid] = s;
  red[tid] = s;
  __syncthreads();
  for (int off = 64; off > 0; off >>= 1) {
    if (tid < off) red[tid] = fmaxf(red[tid], red[tid + off]);
    __syncthreads();
  }
  const float mx = red[0];
  __syncthreads();
  const float e = __expf(at[tid] - mx);
  red[tid] = e;
  __syncthreads();
  for (int off = 64; off > 0; off >>= 1) {
    if (tid < off) red[tid] += red[tid + off];
    __syncthreads();
  }
  const float inv = 1.f / red[0];
  __syncthreads();
  at[tid] = e * inv;
  __syncthreads();
  for (int h = tid; h < 1024; h += 128) {
    float a = 0.f;
    for (int q = 0; q < 128; ++q)
      a += at[q] * qenc[((size_t)b * 128 + q) * 1024 + h];
    qhid[(size_t)bk * 1024 + h] = a;
  }
}

// ------------------------- final epilogue -----------------------------------
__global__ __launch_bounds__(64) void final_kernel(
    const float* __restrict__ A, const float* __restrict__ Bm,
    const float* __restrict__ w2, const float* __restrict__ b2,
    const int* __restrict__ gold_num, const float* __restrict__ qmask,
    float* __restrict__ out)
{
  const int bkq = blockIdx.x;
  const int q = bkq & 127;
  const int k = (bkq >> 7) & 3;
  const int b = bkq >> 9;
  int gn = gold_num[b];
  if (gn > 4) gn = 4;
  const bool act = (k < gn) && (qmask[b * 128 + q] > 0.f);
  const int lane = threadIdx.x;
  const int obase = (b * 4 + k) * 128 + q;
  if (!act) {
    if (lane == 0) {
      out[obase] = -1e30f;          // finite sentinel (ref has -inf; see r1)
      out[16384 + obase] = -1e30f;
    }
    return;
  }
  const float* Ar = A + ((size_t)b * 128 + q) * 1024;
  const float* Br = Bm + (size_t)(b * 4 + k) * 1024;
  float s0 = 0.f, s1 = 0.f;
  for (int o = lane; o < 1024; o += 64) {
    const float v = tanh_f(Ar[o] + Br[o]);
    s0 += v * w2[o];
    s1 += v * w2[1024 + o];
  }
#pragma unroll
  for (int off = 32; off > 0; off >>= 1) {
    s0 += __shfl_down(s0, off, 64);
    s1 += __shfl_down(s1, off, 64);
  }
  if (lane == 0) {
    out[obase] = s0 + b2[0];
    out[16384 + obase] = s1 + b2[1];
  }
}

// ---------------------------------------------------------------------------
extern "C" void kernel_launch(void* const* d_in, const int* in_sizes, int n_in,
                              void* d_out, int out_size, void* d_ws, size_t ws_size,
                              hipStream_t stream)
{
  const float* qe      = (const float*)d_in[0];
  const float* pce     = (const float*)d_in[1];
  const int* gold_num  = (const int*)d_in[2];
  const int* gold_cols = (const int*)d_in[3];
  const int* ncol      = (const int*)d_in[5];
  const float* q_Wih   = (const float*)d_in[6];
  const float* q_Whh   = (const float*)d_in[7];
  const float* q_b     = (const float*)d_in[8];
  const float* c_Wih   = (const float*)d_in[9];
  const float* c_Whh   = (const float*)d_in[10];
  const float* c_b     = (const float*)d_in[11];
  const float* caw     = (const float*)d_in[12];
  const float* cab     = (const float*)d_in[13];
  const float* obaW    = (const float*)d_in[14];
  const float* obab    = (const float*)d_in[15];
  const float* obcW    = (const float*)d_in[16];
  const float* obcb    = (const float*)d_in[17];
  const float* qpW     = (const float*)d_in[18];
  const float* qpb     = (const float*)d_in[19];
  const float* o1W     = (const float*)d_in[20];
  const float* o1b     = (const float*)d_in[21];
  const float* o2W     = (const float*)d_in[22];
  const float* o2b     = (const float*)d_in[23];
  float* outp = (float*)d_out;

  float* ws = (float*)d_ws;
  size_t off = 0;
  float* pre  = ws + off; off += 640UL * 8 * 4096;   // also reused as A matrix
  float* bufA = ws + off; off += 640UL * 8 * 1024;
  float* bufB = ws + off; off += 640UL * 8 * 1024;
  float* colh = ws + off; off += 640UL * 1024;
  float* qmask = ws + off; off += 4096;
  float* cmask = ws + off; off += 5120;
  float* obs  = ws + off; off += 131072;
  float* akey = ws + off; off += 131072;
  float* qhid = ws + off; off += 131072;
  float* vec  = ws + off; off += 262144;
  float* Bm   = ws + off; off += 131072;
  unsigned short* xb = (unsigned short*)(ws + off); off += 2621440;  // bf16 acts
  unsigned short* wb = (unsigned short*)(ws + off); off += 2097152;  // bf16 Wih
  unsigned short* whhq = (unsigned short*)(ws + off); off += 2097152; // q_Whh bf16
  unsigned short* whhc = (unsigned short*)(ws + off); off += 2097152; // c_Whh bf16
  unsigned short* hbuf = (unsigned short*)(ws + off); off += 983040;  // 2 dirs x 3 slabs
  unsigned* bar = (unsigned*)(ws + off); off += 256;  // 16 counters x 64B
  float* Amat = pre;

  const dim3 blk(256);
  auto cvt = [&](const float* src, unsigned short* dst, int n) {
    hipLaunchKernelGGL(f2b_kernel, dim3((n / 4 + 255) / 256), blk, 0, stream,
                       src, dst, n / 4);
  };

  // counters must start at 0 every call (ws is poisoned 0xAA)
  hipMemsetAsync(bar, 0, 1024, stream);

  hipLaunchKernelGGL(mask_kernel, dim3(2304), blk, 0, stream, qe, pce, qmask, cmask);

  // recurrent weights -> bf16 (once)
  cvt(q_Whh, whhq, 4194304);
  cvt(c_Whh, whhc, 4194304);

  // ---- column biLSTM (B=640, T=8): grid (32,8), NT=5 ----
  // entry counters (d*8+bg): +16 per launch
  for (int l = 0; l < 2; ++l) {
    const float* xin = (l == 0) ? pce : bufA;
    float* enc = (l == 0) ? bufA : bufB;
    cvt(xin, xb, 5242880);
    cvt(c_Wih + (size_t)l * 4194304, wb, 4194304);
    hipLaunchKernelGGL(mfma_gemm_kernel, dim3(4096 / 128, 5120 / 128), blk, 0,
                       stream, xb, wb, c_b + l * 4096, pre,
                       1024, 1024, 1024, 0, 4096, 0);
    hipLaunchKernelGGL((lstm_seq_kernel<5>), dim3(32, 8), dim3(512), 0, stream,
                       pre, whhc + (size_t)l * 2 * 2048 * 512, hbuf, enc,
                       8, bar, (unsigned)(l * 16));
  }
  hipLaunchKernelGGL(colpool_kernel, dim3(640), blk, 0, stream,
                     bufB, caw, cab, cmask, colh);
  hipLaunchKernelGGL(gather_kernel, dim3(512), blk, 0, stream,
                     colh, gold_num, gold_cols, ncol, obs);

  // ---- question biLSTM (B=32, T=128): grid (32,1), NT=2 ----
  // entry counters (d,0): at 32 after col launches; +16 per q launch
  for (int l = 0; l < 2; ++l) {
    const float* xin = (l == 0) ? qe : bufA;
    float* enc = (l == 0) ? bufA : bufB;
    cvt(xin, xb, 4194304);
    cvt(q_Wih + (size_t)l * 4194304, wb, 4194304);
    hipLaunchKernelGGL(mfma_gemm_kernel, dim3(4096 / 128, 4096 / 128), blk, 0,
                       stream, xb, wb, q_b + l * 4096, pre,
                       1024, 1024, 1024, 0, 4096, 0);
    hipLaunchKernelGGL((lstm_seq_kernel<2>), dim3(32, 1), dim3(512), 0, stream,
                       pre, whhq + (size_t)l * 2 * 2048 * 512, hbuf, enc,
                       128, bar, (unsigned)(32 + l * 16));
  }
  const float* qenc = bufB;

  // att_key = observed @ ob_attn_W^T + b   (small, fp32 path)
  hipLaunchKernelGGL(gemm_kernel, dim3(16, 2), blk, 0, stream,
                     obs, obaW, obab, akey, 128, 1024, 1024, 1024, 1024, 0, 1024, 0);
  hipLaunchKernelGGL(attn_kernel, dim3(128), dim3(128), 0, stream,
                     akey, qenc, qmask, qhid);
  hipLaunchKernelGGL(gemm_kernel, dim3(16, 2), blk, 0, stream,
                     obs, obcW, obcb, vec, 128, 1024, 1024, 1024, 1024, 0, 2048, 0);
  hipLaunchKernelGGL(gemm_kernel, dim3(16, 2), blk, 0, stream,
                     qhid, qpW, qpb, vec, 128, 1024, 1024, 1024, 1024, 0, 2048, 1024);
  // A = qenc @ out1_W[:, :1024]^T + b1  (bf16 MFMA)
  cvt(qenc, xb, 4194304);
  cvt(o1W, wb, 3145728);
  hipLaunchKernelGGL(mfma_gemm_kernel, dim3(1024 / 128, 4096 / 128), blk, 0,
                     stream, xb, wb, o1b, Amat, 1024, 1024, 3072, 0, 1024, 0);
  // Bm = vec @ out1_W[:, 1024:]^T (fp32 path)
  hipLaunchKernelGGL(gemm_kernel, dim3(16, 2), blk, 0, stream,
                     vec, o1W, nullptr, Bm, 128, 1024, 2048, 2048, 3072, 1024, 1024, 0);
  hipLaunchKernelGGL(final_kernel, dim3(16384), dim3(64), 0, stream,
                     Amat, Bm, o2W, o2b, gold_num, qmask, outp);
}

// Round 7
// 1952.959 us; speedup vs baseline: 1.1072x; 1.0082x over previous
//
#include <hip/hip_runtime.h>
#include <math.h>

// ---------------------------------------------------------------------------
// WhereValuePredictor on MI355X — round 12: revert early-store, fuse f2b.
// r11 post-mortem: early 4B packed h-stores doubled WRITE_SIZE (24.7->49.3MB,
// partial-line writes at the coherence point) and regressed scans 439->477us.
// Revert to r10's cooperative 8B E-phase h stores (full-line writes); KEEP
// r11's poll prefetch (FETCH only +2MB, ~neutral). NEW: fused bf16 outputs —
// lstm writes outb (bf16) directly for GEMM consumers; layer-1 scans skip
// fp32 out entirely. Removes 3 f2b launches + ~80MB traffic + ~36MB dead
// fp32 writes. Protocol unchanged: 3 slabs/dir, bf16-LSB tag (t/3)&1.
// ---------------------------------------------------------------------------

using f32x4 = __attribute__((ext_vector_type(4))) float;
using s16x8 = __attribute__((ext_vector_type(8))) short;
typedef unsigned long long ulong_t;

#define ASYNC_COPY16(gsrc, ldst)                                               \
  __builtin_amdgcn_global_load_lds(                                            \
      (const __attribute__((address_space(1))) void*)(gsrc),                   \
      (__attribute__((address_space(3))) void*)(ldst), 16, 0, 0)

#define LSBM 0x0001000100010001ull

static __device__ __forceinline__ float sigm(float x) {
  return __builtin_amdgcn_rcpf(1.0f + __expf(-x));
}
static __device__ __forceinline__ float tanh_f(float x) {
  return 1.0f - 2.0f * __builtin_amdgcn_rcpf(__expf(2.0f * x) + 1.0f);
}

static __device__ __forceinline__ unsigned short f2b_one(float x) {
  unsigned int u = __float_as_uint(x);
  u = (u + 0x7FFFu + ((u >> 16) & 1u)) >> 16;  // RNE
  return (unsigned short)u;
}

// ------------------------- fp32 -> bf16 convert ----------------------------
__global__ __launch_bounds__(256) void f2b_kernel(
    const float* __restrict__ in, unsigned short* __restrict__ out, int n4)
{
  const int i = blockIdx.x * 256 + threadIdx.x;
  if (i >= n4) return;
  const float4 v = ((const float4*)in)[i];
  ushort4 r;
  r.x = f2b_one(v.x); r.y = f2b_one(v.y);
  r.z = f2b_one(v.z); r.w = f2b_one(v.w);
  ((ushort4*)out)[i] = r;
}

// ------------------------- masks -------------------------------------------
__global__ __launch_bounds__(256) void mask_kernel(
    const float* __restrict__ qe, const float* __restrict__ pce,
    float* __restrict__ qmask, float* __restrict__ cmask)
{
  const int w = threadIdx.x >> 6;
  const int lane = threadIdx.x & 63;
  const int row = blockIdx.x * 4 + w;  // 0..9215
  const float* src = (row < 4096) ? (qe + (size_t)row * 1024)
                                  : (pce + (size_t)(row - 4096) * 1024);
  float s = 0.f;
#pragma unroll
  for (int j = 0; j < 16; ++j) s += fabsf(src[lane + j * 64]);
#pragma unroll
  for (int off = 32; off > 0; off >>= 1) s += __shfl_down(s, off, 64);
  if (lane == 0) {
    const float m = (s != 0.f) ? 1.f : 0.f;
    if (row < 4096) qmask[row] = m;
    else cmask[row - 4096] = m;
  }
}

// ------------------------- bf16 MFMA GEMM (m97-style) ----------------------
__global__ __launch_bounds__(256) void mfma_gemm_kernel(
    const unsigned short* __restrict__ X, const unsigned short* __restrict__ W,
    const float* __restrict__ bias, float* __restrict__ C,
    int K, int ldx, int ldw, int k0w, int ldc, int c0)
{
  __shared__ unsigned short As[128 * 32];
  __shared__ unsigned short Bs[128 * 32];
  const int tid = threadIdx.x;
  const int w = tid >> 6;
  const int l = tid & 63;
  const int m0 = blockIdx.y * 128;
  const int n0 = blockIdx.x * 128;
  const int wm = (w >> 1) * 64;
  const int wn = (w & 1) * 64;

  const unsigned short* xg =
      X + (size_t)(m0 + w * 32 + (l >> 2)) * ldx + (l & 3) * 8;
  const unsigned short* wgp =
      W + (size_t)(n0 + w * 32 + (l >> 2)) * ldw + k0w + (l & 3) * 8;
  unsigned short* asb = As + w * 1024;
  unsigned short* bsb = Bs + w * 1024;

  const int fr = l & 15;
  const int fq = l >> 4;
  const unsigned short* aRd = As + (wm + fr) * 32 + fq * 8;
  const unsigned short* bRd = Bs + (wn + fr) * 32 + fq * 8;

  f32x4 acc[4][4];
#pragma unroll
  for (int i = 0; i < 4; ++i)
#pragma unroll
    for (int j = 0; j < 4; ++j) acc[i][j] = (f32x4){0.f, 0.f, 0.f, 0.f};

  for (int k0 = 0; k0 < K; k0 += 32) {
    ASYNC_COPY16(xg + k0, asb);
    ASYNC_COPY16(xg + (size_t)16 * ldx + k0, asb + 512);
    ASYNC_COPY16(wgp + k0, bsb);
    ASYNC_COPY16(wgp + (size_t)16 * ldw + k0, bsb + 512);
    __syncthreads();
    s16x8 a[4], b[4];
#pragma unroll
    for (int i = 0; i < 4; ++i) a[i] = *(const s16x8*)(aRd + i * 512);
#pragma unroll
    for (int j = 0; j < 4; ++j) b[j] = *(const s16x8*)(bRd + j * 512);
#pragma unroll
    for (int i = 0; i < 4; ++i)
#pragma unroll
      for (int j = 0; j < 4; ++j)
        acc[i][j] = __builtin_amdgcn_mfma_f32_16x16x32_bf16(
            a[i], b[j], acc[i][j], 0, 0, 0);
    __syncthreads();
  }

#pragma unroll
  for (int j = 0; j < 4; ++j) {
    const int col = n0 + wn + j * 16 + fr;
    const float bj = bias ? bias[col] : 0.f;
#pragma unroll
    for (int i = 0; i < 4; ++i) {
      const int row = m0 + wm + i * 16 + fq * 4;
#pragma unroll
      for (int r = 0; r < 4; ++r)
        C[(size_t)(row + r) * ldc + c0 + col] = acc[i][j][r] + bj;
    }
  }
}

// ------------------------- generic fp32 GEMM (small tails) ------------------
__global__ __launch_bounds__(256) void gemm_kernel(
    const float* __restrict__ X, const float* __restrict__ W,
    const float* __restrict__ bias, float* __restrict__ C,
    int M, int N, int K, int ldx, int ldw, int k0w, int ldc, int c0)
{
  __shared__ float Xs[16][68];
  __shared__ float Ws[16][68];
  const int tid = threadIdx.x;
  const int m0 = blockIdx.y * 64;
  const int n0 = blockIdx.x * 64;
  const int lrow = tid >> 2;
  const int lkk = (tid & 3) << 2;
  const float* Xp = X + (size_t)(m0 + lrow) * ldx + lkk;
  const float* Wp = W + (size_t)(n0 + lrow) * ldw + k0w + lkk;
  const int tm = (tid >> 4) << 2;
  const int tn = (tid & 15) << 2;
  float acc[4][4];
#pragma unroll
  for (int i = 0; i < 4; ++i)
#pragma unroll
    for (int j = 0; j < 4; ++j) acc[i][j] = 0.f;

  for (int k0 = 0; k0 < K; k0 += 16) {
    const float4 xv = *(const float4*)(Xp + k0);
    const float4 wv = *(const float4*)(Wp + k0);
    Xs[lkk + 0][lrow] = xv.x; Xs[lkk + 1][lrow] = xv.y;
    Xs[lkk + 2][lrow] = xv.z; Xs[lkk + 3][lrow] = xv.w;
    Ws[lkk + 0][lrow] = wv.x; Ws[lkk + 1][lrow] = wv.y;
    Ws[lkk + 2][lrow] = wv.z; Ws[lkk + 3][lrow] = wv.w;
    __syncthreads();
#pragma unroll
    for (int kk = 0; kk < 16; ++kk) {
      const float4 a4 = *(const float4*)&Xs[kk][tm];
      const float4 b4 = *(const float4*)&Ws[kk][tn];
      const float av[4] = {a4.x, a4.y, a4.z, a4.w};
      const float bv[4] = {b4.x, b4.y, b4.z, b4.w};
#pragma unroll
      for (int i = 0; i < 4; ++i)
#pragma unroll
        for (int j = 0; j < 4; ++j) acc[i][j] += av[i] * bv[j];
    }
    __syncthreads();
  }
  float bvv[4] = {0.f, 0.f, 0.f, 0.f};
  if (bias) {
#pragma unroll
    for (int j = 0; j < 4; ++j) bvv[j] = bias[n0 + tn + j];
  }
#pragma unroll
  for (int i = 0; i < 4; ++i)
#pragma unroll
    for (int j = 0; j < 4; ++j)
      C[(size_t)(m0 + tm + i) * ldc + c0 + n0 + tn + j] = acc[i][j] + bvv[j];
}

// ------------------------- persistent LSTM scan (parity-tag poll) -----------
// Grid (32, BG): blockIdx.x = dir*16 + unit-slice w. blockIdx.y = batch
// group. 3 slabs/dir; h(t) -> slab t%3 with bf16-LSB tag (t/3)&1 (no
// clears; slab reuse flips tag). Consumer polls slab (t+2)%3 for tag
// ((t-1)/3)&1 — successful poll IS the data; poll loads prefetched in E.
// h stores: cooperative 8B ulong (full-line write-combine) in E from hS.
// out (fp32) and outb (bf16) are optional fused outputs (null = skip).
// Per step: C{check/retry -> hR; pv loads} B1 D{MFMA+state -> hS,hnreg}
// B2 E{preS<-pv; h stores; out/outb; poll prefetch}. Raw s_barrier +
// lgkmcnt(0) only on the critical path.
template <int NT>
__global__ __launch_bounds__(512) void lstm_seq_kernel(
    const float* __restrict__ pre,           // [Bn][T][4096]
    const unsigned short* __restrict__ whh,  // bf16 [2 dirs][2048][512]
    unsigned short* __restrict__ hbuf,       // bf16 [2 dirs][3 slabs][640][512]
    float* __restrict__ out,                 // [Bn][T][1024] fp32 (or null)
    unsigned short* __restrict__ outb,       // [Bn][T][1024] bf16 (or null)
    int T, unsigned* __restrict__ bar, unsigned base)
{
  __shared__ float preS[NT][4][16][34];      // [nt][gate][n][unit+pad]
  __shared__ float Tr[8][4][4][20];          // [wave][gate][du+pad][n]
  __shared__ unsigned short hS[NT * 16][36]; // [n_local][unit+pad] (write stg)
  __shared__ unsigned short hR[NT * 16][528];// [n_local][unit] (1056B stride)
  const int tid = threadIdx.x;               // 0..511
  const int v = tid >> 6;                    // wave 0..7
  const int l = tid & 63;
  const int d = blockIdx.x >> 4;
  const int w = blockIdx.x & 15;             // slice: units w*32..+31
  const int bg = blockIdx.y;
  const int fr = l & 15;
  const int fq = l >> 4;
  const int ubase = w * 32;
  const int unit = ubase + v * 4 + fq;
  const int nbase = bg * (NT * 16);
  const size_t SLOT = (size_t)640 * 512;
  unsigned* ctr = bar + (d * 8 + bg) * 16;   // 64B-spaced counters
  unsigned short* sl = hbuf + (size_t)d * 3 * SLOT;  // this dir's 3 slabs

  // A-frags: MFMA A row m=fr -> whh row (m>>2)*512 + ubase + v*4 + (m&3)
  s16x8 afr[16];
  {
    const unsigned short* arow = whh + (size_t)d * 2048 * 512 +
        ((size_t)(fr >> 2) * 512 + ubase + v * 4 + (fr & 3)) * 512 + fq * 8;
#pragma unroll
    for (int kk = 0; kk < 16; ++kk)
      afr[kk] = *(const s16x8*)(arow + kk * 32);
  }

  float creg[NT];
#pragma unroll
  for (int i = 0; i < NT; ++i) creg[i] = 0.f;

  // staging thread mapping: one float4 per thread per nt
  const int sc = tid & 7;
  const int sn = (tid >> 3) & 15;
  const int sg = tid >> 7;

  // ---- prologue: pre-clear own stripe in all 3 slabs with LSB=1 ----
  // (first tags used are (t/3)&1 = 0 for t=0,1,2 -> LSB=1 can't false-match)
  for (int s = 0; s < 3; ++s) {
    ulong_t* cb = (ulong_t*)(sl + (size_t)s * SLOT + (size_t)nbase * 512 + ubase);
    for (int i = tid; i < NT * 16 * 8; i += 512)
      __hip_atomic_store(cb + (size_t)(i >> 3) * 128 + (i & 7), LSBM,
                         __ATOMIC_RELAXED, __HIP_MEMORY_SCOPE_AGENT);
  }
  // ---- prologue: stage pre for t=0 ----
  {
    const int tt0 = d ? (T - 1) : 0;
#pragma unroll
    for (int nt = 0; nt < NT; ++nt) {
      const int n = nbase + nt * 16 + sn;
      const float4 pv = *(const float4*)(
          pre + ((size_t)n * T + tt0) * 4096 + d * 2048 + sg * 512 + ubase +
          sc * 4);
      *(float4*)&preS[nt][sg][sn][sc * 4] = pv;
    }
  }
  __syncthreads();  // drains pre-clears (vmcnt0 per wave) + preS lgkm
  // ---- launch-entry barrier: all 16 WGs of (d,bg) pre-cleared ----
  if (tid == 0) {
    __hip_atomic_fetch_add(ctr, 1u, __ATOMIC_RELAXED,
                           __HIP_MEMORY_SCOPE_AGENT);
    const unsigned target = base + 16u;
    long spins = 0;
    while (__hip_atomic_load(ctr, __ATOMIC_RELAXED,
                             __HIP_MEMORY_SCOPE_AGENT) < target) {
      __builtin_amdgcn_s_sleep(1);
      if (++spins > 2000000L) break;  // safety valve
    }
  }
  __syncthreads();

  float hnreg[NT];
  ulong_t u[4 * NT];  // poll data, prefetched in E, checked/used in C
  for (int t = 0; t < T; ++t) {
    const int tt = d ? (T - 1 - t) : t;
    const unsigned wtag = (unsigned)((t / 3) & 1);        // tag for h(t)
    unsigned short* wr = sl + (size_t)(t % 3) * SLOT;     // h(t) slab

    // ---- C: validate prefetched h(t-1); retry-poll if stale; -> hR ----
    if (t > 0) {
      const unsigned rtag = (unsigned)(((t - 1) / 3) & 1);
      const ulong_t want = rtag ? LSBM : 0ull;
      const ulong_t* hq =
          (const ulong_t*)(sl + (size_t)((t + 2) % 3) * SLOT) +
          (size_t)nbase * 128;
      bool bad0 = false;
#pragma unroll
      for (int i = 0; i < 4 * NT; ++i) bad0 |= ((u[i] & LSBM) != want);
      if (bad0) {
        bool ok = false;
        int it = 0;
        while (!ok && it < 200000) {
#pragma unroll
          for (int i = 0; i < 2 * NT; ++i) {
            const int cid = i * 512 + tid;                 // 16B chunk id
            const ulong_t* p = hq + (size_t)(cid >> 6) * 128 + (cid & 63) * 2;
            u[2 * i] = __hip_atomic_load(p, __ATOMIC_RELAXED,
                                         __HIP_MEMORY_SCOPE_AGENT);
            u[2 * i + 1] = __hip_atomic_load(p + 1, __ATOMIC_RELAXED,
                                             __HIP_MEMORY_SCOPE_AGENT);
          }
          bool bad = false;
#pragma unroll
          for (int i = 0; i < 4 * NT; ++i) bad |= ((u[i] & LSBM) != want);
          ok = !bad;
          ++it;
          if (!ok && it > 8) __builtin_amdgcn_s_sleep(1);
        }
      }
#pragma unroll
      for (int i = 0; i < 2 * NT; ++i) {
        const int cid = i * 512 + tid;
        ulong_t* dst = (ulong_t*)&hR[cid >> 6][(cid & 63) * 8];
        dst[0] = u[2 * i];
        dst[1] = u[2 * i + 1];
      }
    }
    // ---- pv prefetch: pre(t+1) into registers ----
    float4 pv[NT];
    if (t + 1 < T) {
      const int ttn = d ? (T - 2 - t) : (t + 1);
#pragma unroll
      for (int nt = 0; nt < NT; ++nt) {
        const int n = nbase + nt * 16 + sn;
        pv[nt] = *(const float4*)(
            pre + ((size_t)n * T + ttn) * 4096 + d * 2048 + sg * 512 + ubase +
            sc * 4);
      }
    }
    // ---- B1: hR (and E(t-1)'s preS writes) visible to all waves ----
    asm volatile("s_waitcnt lgkmcnt(0)" ::: "memory");
    __builtin_amdgcn_s_barrier();
    __builtin_amdgcn_sched_barrier(0);

    // ---- D: gates + state update ----
#pragma unroll
    for (int nt = 0; nt < NT; ++nt) {
      f32x4 acc = (f32x4){0.f, 0.f, 0.f, 0.f};
      if (t > 0) {
        const unsigned short* bRd = &hR[nt * 16 + fr][fq * 8];
#pragma unroll
        for (int kk = 0; kk < 16; ++kk) {
          const s16x8 bv = *(const s16x8*)(bRd + kk * 32);
          acc = __builtin_amdgcn_mfma_f32_16x16x32_bf16(afr[kk], bv, acc,
                                                        0, 0, 0);
        }
      }
      // wave-local transpose (C row fq*4+r -> gate fq, du r; col fr -> n)
#pragma unroll
      for (int r = 0; r < 4; ++r) Tr[v][fq][r][fr] = acc[r];
      const int uu = v * 4 + fq;
      const float gi = Tr[v][0][fq][fr] + preS[nt][0][fr][uu];
      const float gf = Tr[v][1][fq][fr] + preS[nt][1][fr][uu];
      const float gg = Tr[v][2][fq][fr] + preS[nt][2][fr][uu];
      const float go = Tr[v][3][fq][fr] + preS[nt][3][fr][uu];
      const float cn = sigm(gf) * creg[nt] + sigm(gi) * tanh_f(gg);
      const float hn = sigm(go) * tanh_f(cn);
      creg[nt] = cn;
      hnreg[nt] = hn;
      hS[nt * 16 + fr][uu] =
          (unsigned short)((f2b_one(hn) & 0xFFFEu) | wtag);
    }
    // ---- B2: hS ready; preS fully consumed; hR consumed ----
    asm volatile("s_waitcnt lgkmcnt(0)" ::: "memory");
    __builtin_amdgcn_s_barrier();
    __builtin_amdgcn_sched_barrier(0);

    // ---- E: preS <- pv; cooperative h stores; out/outb; poll prefetch ----
    if (t + 1 < T) {
#pragma unroll
      for (int nt = 0; nt < NT; ++nt)
        *(float4*)&preS[nt][sg][sn][sc * 4] = pv[nt];
    }
    {
      const int un = tid & 7;       // ulong within 32-unit slice
      const int nl = tid >> 3;      // 0..63
      for (int p = nl; p < NT * 16; p += 64) {
        const ulong_t val = *(const ulong_t*)&hS[p][un * 4];
        __hip_atomic_store(
            (ulong_t*)(wr + (size_t)(nbase + p) * 512 + ubase) + un, val,
            __ATOMIC_RELAXED, __HIP_MEMORY_SCOPE_AGENT);
      }
    }
    if (out) {
#pragma unroll
      for (int nt = 0; nt < NT; ++nt) {
        const int n = nbase + nt * 16 + fr;
        out[((size_t)n * T + tt) * 1024 + d * 512 + unit] = hnreg[nt];
      }
    }
    if (outb) {
#pragma unroll
      for (int nt = 0; nt < NT; ++nt) {
        const int n = nbase + nt * 16 + fr;
        outb[((size_t)n * T + tt) * 1024 + d * 512 + unit] =
            f2b_one(hnreg[nt]);
      }
    }
    if (t + 1 < T) {
      // prefetch next step's poll loads (consumer slab for C(t+1) = t%3)
      const ulong_t* hq =
          (const ulong_t*)(sl + (size_t)(t % 3) * SLOT) + (size_t)nbase * 128;
#pragma unroll
      for (int i = 0; i < 2 * NT; ++i) {
        const int cid = i * 512 + tid;
        const ulong_t* p = hq + (size_t)(cid >> 6) * 128 + (cid & 63) * 2;
        u[2 * i] = __hip_atomic_load(p, __ATOMIC_RELAXED,
                                     __HIP_MEMORY_SCOPE_AGENT);
        u[2 * i + 1] = __hip_atomic_load(p + 1, __ATOMIC_RELAXED,
                                         __HIP_MEMORY_SCOPE_AGENT);
      }
    }
  }
}

// ------------------------- column attention pool ----------------------------
__global__ __launch_bounds__(256) void colpool_kernel(
    const float* __restrict__ cenc, const float* __restrict__ caw,
    const float* __restrict__ cab, const float* __restrict__ cmask,
    float* __restrict__ colh)
{
  __shared__ float part[8][33];
  __shared__ float wbuf[8];
  const int p = blockIdx.x;
  const int t = threadIdx.x >> 5;
  const int ln = threadIdx.x & 31;
  const float* row = cenc + ((size_t)p * 8 + t) * 1024;
  float s = 0.f;
  for (int j = ln; j < 1024; j += 32) s += row[j] * caw[j];
  part[t][ln] = s;
  __syncthreads();
  if (threadIdx.x < 8) {
    float lg = 0.f;
    for (int i = 0; i < 32; ++i) lg += part[threadIdx.x][i];
    lg += cab[0];
    wbuf[threadIdx.x] = (cmask[p * 8 + threadIdx.x] > 0.f) ? lg : -INFINITY;
  }
  __syncthreads();
  if (threadIdx.x == 0) {
    float mx = -INFINITY;
    for (int i = 0; i < 8; ++i) mx = fmaxf(mx, wbuf[i]);
    float e[8];
    float sum = 0.f;
    for (int i = 0; i < 8; ++i) { e[i] = __expf(wbuf[i] - mx); sum += e[i]; }
    for (int i = 0; i < 8; ++i) wbuf[i] = e[i] / sum;
  }
  __syncthreads();
  for (int h = threadIdx.x; h < 1024; h += 256) {
    float a = 0.f;
#pragma unroll
    for (int i = 0; i < 8; ++i) a += wbuf[i] * cenc[((size_t)p * 8 + i) * 1024 + h];
    colh[(size_t)p * 1024 + h] = a;
  }
}

// ------------------------- gather observed ----------------------------------
__global__ __launch_bounds__(256) void gather_kernel(
    const float* __restrict__ colh, const int* __restrict__ gold_num,
    const int* __restrict__ gold_cols, const int* __restrict__ ncol,
    float* __restrict__ obs)
{
  const int idx = blockIdx.x * 256 + threadIdx.x;
  const int h = idx & 1023;
  const int k = (idx >> 10) & 3;
  const int b = idx >> 12;
  int gn = gold_num[b];
  if (gn > 4) gn = 4;
  const float m = (k < gn) ? 1.f : 0.f;
  const int col = gold_cols[b * 4 + k];
  const int NC = ncol[0];
  obs[idx] = m * colh[(size_t)(b * NC + col) * 1024 + h];
}

// ------------------------- fused attention (per b,k) ------------------------
__global__ __launch_bounds__(128) void attn_kernel(
    const float* __restrict__ akey, const float* __restrict__ qenc,
    const float* __restrict__ qmask, float* __restrict__ qhid)
{
  __shared__ float ak[1024];
  __shared__ float red[128];
  __shared__ float at[128];
  const int bk = blockIdx.x;
  const int b = bk >> 2;
  const int tid = threadIdx.x;
  for (int i = tid; i < 1024; i += 128) ak[i] = akey[(size_t)bk * 1024 + i];
  __syncthreads();
  const float* qrow = qenc + ((size_t)b * 128 + tid) * 1024;
  float s = 0.f;
  for (int hh = 0; hh < 1024; hh += 4) {
    const float4 qv = *(const float4*)(qrow + hh);
    s += ak[hh] * qv.x + ak[hh + 1] * qv.y + ak[hh + 2] * qv.z + ak[hh + 3] * qv.w;
  }
  s = (qmask[b * 128 + tid] > 0.f) ? s : -INFINITY;
  at[tid] = s;
  red[tid] = s;
  __syncthreads();
  for (int off = 64; off > 0; off >>= 1) {
    if (tid < off) red[tid] = fmaxf(red[tid], red[tid + off]);
    __syncthreads();
  }
  const float mx = red[0];
  __syncthreads();
  const float e = __expf(at[tid] - mx);
  red[tid] = e;
  __syncthreads();
  for (int off = 64; off > 0; off >>= 1) {
    if (tid < off) red[tid] += red[tid + off];
    __syncthreads();
  }
  const float inv = 1.f / red[0];
  __syncthreads();
  at[tid] = e * inv;
  __syncthreads();
  for (int h = tid; h < 1024; h += 128) {
    float a = 0.f;
    for (int q = 0; q < 128; ++q)
      a += at[q] * qenc[((size_t)b * 128 + q) * 1024 + h];
    qhid[(size_t)bk * 1024 + h] = a;
  }
}

// ------------------------- final epilogue -----------------------------------
__global__ __launch_bounds__(64) void final_kernel(
    const float* __restrict__ A, const float* __restrict__ Bm,
    const float* __restrict__ w2, const float* __restrict__ b2,
    const int* __restrict__ gold_num, const float* __restrict__ qmask,
    float* __restrict__ out)
{
  const int bkq = blockIdx.x;
  const int q = bkq & 127;
  const int k = (bkq >> 7) & 3;
  const int b = bkq >> 9;
  int gn = gold_num[b];
  if (gn > 4) gn = 4;
  const bool act = (k < gn) && (qmask[b * 128 + q] > 0.f);
  const int lane = threadIdx.x;
  const int obase = (b * 4 + k) * 128 + q;
  if (!act) {
    if (lane == 0) {
      out[obase] = -1e30f;          // finite sentinel (ref has -inf; see r1)
      out[16384 + obase] = -1e30f;
    }
    return;
  }
  const float* Ar = A + ((size_t)b * 128 + q) * 1024;
  const float* Br = Bm + (size_t)(b * 4 + k) * 1024;
  float s0 = 0.f, s1 = 0.f;
  for (int o = lane; o < 1024; o += 64) {
    const float v = tanh_f(Ar[o] + Br[o]);
    s0 += v * w2[o];
    s1 += v * w2[1024 + o];
  }
#pragma unroll
  for (int off = 32; off > 0; off >>= 1) {
    s0 += __shfl_down(s0, off, 64);
    s1 += __shfl_down(s1, off, 64);
  }
  if (lane == 0) {
    out[obase] = s0 + b2[0];
    out[16384 + obase] = s1 + b2[1];
  }
}

// ---------------------------------------------------------------------------
extern "C" void kernel_launch(void* const* d_in, const int* in_sizes, int n_in,
                              void* d_out, int out_size, void* d_ws, size_t ws_size,
                              hipStream_t stream)
{
  const float* qe      = (const float*)d_in[0];
  const float* pce     = (const float*)d_in[1];
  const int* gold_num  = (const int*)d_in[2];
  const int* gold_cols = (const int*)d_in[3];
  const int* ncol      = (const int*)d_in[5];
  const float* q_Wih   = (const float*)d_in[6];
  const float* q_Whh   = (const float*)d_in[7];
  const float* q_b     = (const float*)d_in[8];
  const float* c_Wih   = (const float*)d_in[9];
  const float* c_Whh   = (const float*)d_in[10];
  const float* c_b     = (const float*)d_in[11];
  const float* caw     = (const float*)d_in[12];
  const float* cab     = (const float*)d_in[13];
  const float* obaW    = (const float*)d_in[14];
  const float* obab    = (const float*)d_in[15];
  const float* obcW    = (const float*)d_in[16];
  const float* obcb    = (const float*)d_in[17];
  const float* qpW     = (const float*)d_in[18];
  const float* qpb     = (const float*)d_in[19];
  const float* o1W     = (const float*)d_in[20];
  const float* o1b     = (const float*)d_in[21];
  const float* o2W     = (const float*)d_in[22];
  const float* o2b     = (const float*)d_in[23];
  float* outp = (float*)d_out;

  float* ws = (float*)d_ws;
  size_t off = 0;
  float* pre  = ws + off; off += 640UL * 8 * 4096;   // also reused as A matrix
  float* bufA = ws + off; off += 640UL * 8 * 1024;   // (unused after fusion)
  float* bufB = ws + off; off += 640UL * 8 * 1024;
  float* colh = ws + off; off += 640UL * 1024;
  float* qmask = ws + off; off += 4096;
  float* cmask = ws + off; off += 5120;
  float* obs  = ws + off; off += 131072;
  float* akey = ws + off; off += 131072;
  float* qhid = ws + off; off += 131072;
  float* vec  = ws + off; off += 262144;
  float* Bm   = ws + off; off += 131072;
  unsigned short* xb = (unsigned short*)(ws + off); off += 2621440;  // bf16 acts
  unsigned short* wb = (unsigned short*)(ws + off); off += 2097152;  // bf16 Wih
  unsigned short* whhq = (unsigned short*)(ws + off); off += 2097152; // q_Whh bf16
  unsigned short* whhc = (unsigned short*)(ws + off); off += 2097152; // c_Whh bf16
  unsigned short* hbuf = (unsigned short*)(ws + off); off += 983040;  // 2 dirs x 3 slabs
  unsigned* bar = (unsigned*)(ws + off); off += 256;  // 16 counters x 64B
  float* Amat = pre;
  (void)bufA;

  const dim3 blk(256);
  auto cvt = [&](const float* src, unsigned short* dst, int n) {
    hipLaunchKernelGGL(f2b_kernel, dim3((n / 4 + 255) / 256), blk, 0, stream,
                       src, dst, n / 4);
  };

  // counters must start at 0 every call (ws is poisoned 0xAA)
  hipMemsetAsync(bar, 0, 1024, stream);

  hipLaunchKernelGGL(mask_kernel, dim3(2304), blk, 0, stream, qe, pce, qmask, cmask);

  // recurrent weights -> bf16 (once)
  cvt(q_Whh, whhq, 4194304);
  cvt(c_Whh, whhc, 4194304);

  // ---- column biLSTM (B=640, T=8): grid (32,8), NT=5 ----
  // layer 0: input cvt; scan emits bf16 directly into xb (no fp32 out)
  cvt(pce, xb, 5242880);
  cvt(c_Wih, wb, 4194304);
  hipLaunchKernelGGL(mfma_gemm_kernel, dim3(4096 / 128, 5120 / 128), blk, 0,
                     stream, xb, wb, c_b, pre, 1024, 1024, 1024, 0, 4096, 0);
  hipLaunchKernelGGL((lstm_seq_kernel<5>), dim3(32, 8), dim3(512), 0, stream,
                     pre, whhc, hbuf, (float*)nullptr, xb, 8, bar, 0u);
  // layer 1: reads xb (bf16 from scan); emits fp32 bufB only
  cvt(c_Wih + 4194304, wb, 4194304);
  hipLaunchKernelGGL(mfma_gemm_kernel, dim3(4096 / 128, 5120 / 128), blk, 0,
                     stream, xb, wb, c_b + 4096, pre, 1024, 1024, 1024, 0, 4096, 0);
  hipLaunchKernelGGL((lstm_seq_kernel<5>), dim3(32, 8), dim3(512), 0, stream,
                     pre, whhc + (size_t)2 * 2048 * 512, hbuf, bufB,
                     (unsigned short*)nullptr, 8, bar, 16u);
  hipLaunchKernelGGL(colpool_kernel, dim3(640), blk, 0, stream,
                     bufB, caw, cab, cmask, colh);
  hipLaunchKernelGGL(gather_kernel, dim3(512), blk, 0, stream,
                     colh, gold_num, gold_cols, ncol, obs);

  // ---- question biLSTM (B=32, T=128): grid (32,1), NT=2 ----
  // layer 0: input cvt; scan emits bf16 into xb only
  cvt(qe, xb, 4194304);
  cvt(q_Wih, wb, 4194304);
  hipLaunchKernelGGL(mfma_gemm_kernel, dim3(4096 / 128, 4096 / 128), blk, 0,
                     stream, xb, wb, q_b, pre, 1024, 1024, 1024, 0, 4096, 0);
  hipLaunchKernelGGL((lstm_seq_kernel<2>), dim3(32, 1), dim3(512), 0, stream,
                     pre, whhq, hbuf, (float*)nullptr, xb, 128, bar, 32u);
  // layer 1: reads xb; emits fp32 bufB (attn/gemms) + bf16 xb (o1 GEMM)
  cvt(q_Wih + 4194304, wb, 4194304);
  hipLaunchKernelGGL(mfma_gemm_kernel, dim3(4096 / 128, 4096 / 128), blk, 0,
                     stream, xb, wb, q_b + 4096, pre, 1024, 1024, 1024, 0, 4096, 0);
  hipLaunchKernelGGL((lstm_seq_kernel<2>), dim3(32, 1), dim3(512), 0, stream,
                     pre, whhq + (size_t)2 * 2048 * 512, hbuf, bufB, xb,
                     128, bar, 48u);
  const float* qenc = bufB;

  // att_key = observed @ ob_attn_W^T + b   (small, fp32 path)
  hipLaunchKernelGGL(gemm_kernel, dim3(16, 2), blk, 0, stream,
                     obs, obaW, obab, akey, 128, 1024, 1024, 1024, 1024, 0, 1024, 0);
  hipLaunchKernelGGL(attn_kernel, dim3(128), dim3(128), 0, stream,
                     akey, qenc, qmask, qhid);
  hipLaunchKernelGGL(gemm_kernel, dim3(16, 2), blk, 0, stream,
                     obs, obcW, obcb, vec, 128, 1024, 1024, 1024, 1024, 0, 2048, 0);
  hipLaunchKernelGGL(gemm_kernel, dim3(16, 2), blk, 0, stream,
                     qhid, qpW, qpb, vec, 128, 1024, 1024, 1024, 1024, 0, 2048, 1024);
  // A = qenc @ out1_W[:, :1024]^T + b1  (bf16 MFMA; xb = qenc bf16 from scan)
  cvt(o1W, wb, 3145728);
  hipLaunchKernelGGL(mfma_gemm_kernel, dim3(1024 / 128, 4096 / 128), blk, 0,
                     stream, xb, wb, o1b, Amat, 1024, 1024, 3072, 0, 1024, 0);
  // Bm = vec @ out1_W[:, 1024:]^T (fp32 path)
  hipLaunchKernelGGL(gemm_kernel, dim3(16, 2), blk, 0, stream,
                     vec, o1W, nullptr, Bm, 128, 1024, 2048, 2048, 3072, 1024, 1024, 0);
  hipLaunchKernelGGL(final_kernel, dim3(16384), dim3(64), 0, stream,
                     Amat, Bm, o2W, o2b, gold_num, qmask, outp);
}

// Round 8
// 1829.941 us; speedup vs baseline: 1.1816x; 1.0672x over previous
//
#include <hip/hip_runtime.h>
#include <math.h>

// ---------------------------------------------------------------------------
// WhereValuePredictor on MI355X — round 13: drop poll-prefetch, coalesce outb.
// r12 post-mortem: layer-1 q-scans 490us (worse than r10's 439) with FETCH
// identical to r10 -> the E-phase poll prefetch is net-negative (samples the
// slab while producers still store -> stale -> pays vmcnt wait + full retry).
// outb 2B scattered stores raised WRITE 24.8->33MB (partial lines). Fix:
// (a) C = r10-style direct poll (no carried u[]); (b) outb stored
// cooperatively as 8B ulongs from hS (full-line, tag rides along <=1ulp);
// (c) h stores issued first in E. Protocol unchanged: 3 slabs/dir,
// bf16-LSB tag (t/3)&1, no clears, fused f2b outputs.
// ---------------------------------------------------------------------------

using f32x4 = __attribute__((ext_vector_type(4))) float;
using s16x8 = __attribute__((ext_vector_type(8))) short;
typedef unsigned long long ulong_t;

#define ASYNC_COPY16(gsrc, ldst)                                               \
  __builtin_amdgcn_global_load_lds(                                            \
      (const __attribute__((address_space(1))) void*)(gsrc),                   \
      (__attribute__((address_space(3))) void*)(ldst), 16, 0, 0)

#define LSBM 0x0001000100010001ull

static __device__ __forceinline__ float sigm(float x) {
  return __builtin_amdgcn_rcpf(1.0f + __expf(-x));
}
static __device__ __forceinline__ float tanh_f(float x) {
  return 1.0f - 2.0f * __builtin_amdgcn_rcpf(__expf(2.0f * x) + 1.0f);
}

static __device__ __forceinline__ unsigned short f2b_one(float x) {
  unsigned int u = __float_as_uint(x);
  u = (u + 0x7FFFu + ((u >> 16) & 1u)) >> 16;  // RNE
  return (unsigned short)u;
}

// ------------------------- fp32 -> bf16 convert ----------------------------
__global__ __launch_bounds__(256) void f2b_kernel(
    const float* __restrict__ in, unsigned short* __restrict__ out, int n4)
{
  const int i = blockIdx.x * 256 + threadIdx.x;
  if (i >= n4) return;
  const float4 v = ((const float4*)in)[i];
  ushort4 r;
  r.x = f2b_one(v.x); r.y = f2b_one(v.y);
  r.z = f2b_one(v.z); r.w = f2b_one(v.w);
  ((ushort4*)out)[i] = r;
}

// ------------------------- masks -------------------------------------------
__global__ __launch_bounds__(256) void mask_kernel(
    const float* __restrict__ qe, const float* __restrict__ pce,
    float* __restrict__ qmask, float* __restrict__ cmask)
{
  const int w = threadIdx.x >> 6;
  const int lane = threadIdx.x & 63;
  const int row = blockIdx.x * 4 + w;  // 0..9215
  const float* src = (row < 4096) ? (qe + (size_t)row * 1024)
                                  : (pce + (size_t)(row - 4096) * 1024);
  float s = 0.f;
#pragma unroll
  for (int j = 0; j < 16; ++j) s += fabsf(src[lane + j * 64]);
#pragma unroll
  for (int off = 32; off > 0; off >>= 1) s += __shfl_down(s, off, 64);
  if (lane == 0) {
    const float m = (s != 0.f) ? 1.f : 0.f;
    if (row < 4096) qmask[row] = m;
    else cmask[row - 4096] = m;
  }
}

// ------------------------- bf16 MFMA GEMM (m97-style) ----------------------
__global__ __launch_bounds__(256) void mfma_gemm_kernel(
    const unsigned short* __restrict__ X, const unsigned short* __restrict__ W,
    const float* __restrict__ bias, float* __restrict__ C,
    int K, int ldx, int ldw, int k0w, int ldc, int c0)
{
  __shared__ unsigned short As[128 * 32];
  __shared__ unsigned short Bs[128 * 32];
  const int tid = threadIdx.x;
  const int w = tid >> 6;
  const int l = tid & 63;
  const int m0 = blockIdx.y * 128;
  const int n0 = blockIdx.x * 128;
  const int wm = (w >> 1) * 64;
  const int wn = (w & 1) * 64;

  const unsigned short* xg =
      X + (size_t)(m0 + w * 32 + (l >> 2)) * ldx + (l & 3) * 8;
  const unsigned short* wgp =
      W + (size_t)(n0 + w * 32 + (l >> 2)) * ldw + k0w + (l & 3) * 8;
  unsigned short* asb = As + w * 1024;
  unsigned short* bsb = Bs + w * 1024;

  const int fr = l & 15;
  const int fq = l >> 4;
  const unsigned short* aRd = As + (wm + fr) * 32 + fq * 8;
  const unsigned short* bRd = Bs + (wn + fr) * 32 + fq * 8;

  f32x4 acc[4][4];
#pragma unroll
  for (int i = 0; i < 4; ++i)
#pragma unroll
    for (int j = 0; j < 4; ++j) acc[i][j] = (f32x4){0.f, 0.f, 0.f, 0.f};

  for (int k0 = 0; k0 < K; k0 += 32) {
    ASYNC_COPY16(xg + k0, asb);
    ASYNC_COPY16(xg + (size_t)16 * ldx + k0, asb + 512);
    ASYNC_COPY16(wgp + k0, bsb);
    ASYNC_COPY16(wgp + (size_t)16 * ldw + k0, bsb + 512);
    __syncthreads();
    s16x8 a[4], b[4];
#pragma unroll
    for (int i = 0; i < 4; ++i) a[i] = *(const s16x8*)(aRd + i * 512);
#pragma unroll
    for (int j = 0; j < 4; ++j) b[j] = *(const s16x8*)(bRd + j * 512);
#pragma unroll
    for (int i = 0; i < 4; ++i)
#pragma unroll
      for (int j = 0; j < 4; ++j)
        acc[i][j] = __builtin_amdgcn_mfma_f32_16x16x32_bf16(
            a[i], b[j], acc[i][j], 0, 0, 0);
    __syncthreads();
  }

#pragma unroll
  for (int j = 0; j < 4; ++j) {
    const int col = n0 + wn + j * 16 + fr;
    const float bj = bias ? bias[col] : 0.f;
#pragma unroll
    for (int i = 0; i < 4; ++i) {
      const int row = m0 + wm + i * 16 + fq * 4;
#pragma unroll
      for (int r = 0; r < 4; ++r)
        C[(size_t)(row + r) * ldc + c0 + col] = acc[i][j][r] + bj;
    }
  }
}

// ------------------------- generic fp32 GEMM (small tails) ------------------
__global__ __launch_bounds__(256) void gemm_kernel(
    const float* __restrict__ X, const float* __restrict__ W,
    const float* __restrict__ bias, float* __restrict__ C,
    int M, int N, int K, int ldx, int ldw, int k0w, int ldc, int c0)
{
  __shared__ float Xs[16][68];
  __shared__ float Ws[16][68];
  const int tid = threadIdx.x;
  const int m0 = blockIdx.y * 64;
  const int n0 = blockIdx.x * 64;
  const int lrow = tid >> 2;
  const int lkk = (tid & 3) << 2;
  const float* Xp = X + (size_t)(m0 + lrow) * ldx + lkk;
  const float* Wp = W + (size_t)(n0 + lrow) * ldw + k0w + lkk;
  const int tm = (tid >> 4) << 2;
  const int tn = (tid & 15) << 2;
  float acc[4][4];
#pragma unroll
  for (int i = 0; i < 4; ++i)
#pragma unroll
    for (int j = 0; j < 4; ++j) acc[i][j] = 0.f;

  for (int k0 = 0; k0 < K; k0 += 16) {
    const float4 xv = *(const float4*)(Xp + k0);
    const float4 wv = *(const float4*)(Wp + k0);
    Xs[lkk + 0][lrow] = xv.x; Xs[lkk + 1][lrow] = xv.y;
    Xs[lkk + 2][lrow] = xv.z; Xs[lkk + 3][lrow] = xv.w;
    Ws[lkk + 0][lrow] = wv.x; Ws[lkk + 1][lrow] = wv.y;
    Ws[lkk + 2][lrow] = wv.z; Ws[lkk + 3][lrow] = wv.w;
    __syncthreads();
#pragma unroll
    for (int kk = 0; kk < 16; ++kk) {
      const float4 a4 = *(const float4*)&Xs[kk][tm];
      const float4 b4 = *(const float4*)&Ws[kk][tn];
      const float av[4] = {a4.x, a4.y, a4.z, a4.w};
      const float bv[4] = {b4.x, b4.y, b4.z, b4.w};
#pragma unroll
      for (int i = 0; i < 4; ++i)
#pragma unroll
        for (int j = 0; j < 4; ++j) acc[i][j] += av[i] * bv[j];
    }
    __syncthreads();
  }
  float bvv[4] = {0.f, 0.f, 0.f, 0.f};
  if (bias) {
#pragma unroll
    for (int j = 0; j < 4; ++j) bvv[j] = bias[n0 + tn + j];
  }
#pragma unroll
  for (int i = 0; i < 4; ++i)
#pragma unroll
    for (int j = 0; j < 4; ++j)
      C[(size_t)(m0 + tm + i) * ldc + c0 + n0 + tn + j] = acc[i][j] + bvv[j];
}

// ------------------------- persistent LSTM scan (parity-tag poll) -----------
// Grid (32, BG): blockIdx.x = dir*16 + unit-slice w. blockIdx.y = batch
// group. 3 slabs/dir; h(t) -> slab t%3 with bf16-LSB tag (t/3)&1 (no
// clears; slab reuse flips tag). Consumer polls slab (t+2)%3 for tag
// ((t-1)/3)&1 — successful poll IS the data (direct poll, no prefetch:
// r12 showed prefetch is net-negative, stale >90% + vmcnt wait).
// h stores: cooperative 8B ulong (full-line) in E from hS, issued FIRST.
// outb (bf16) also cooperative 8B from hS; out (fp32) per-thread.
// Per step: C{poll -> hR; pv loads} B1 D{MFMA+state -> hS,hnreg} B2
// E{h stores; preS<-pv; outb; out}. Raw s_barrier + lgkmcnt(0) only.
template <int NT>
__global__ __launch_bounds__(512) void lstm_seq_kernel(
    const float* __restrict__ pre,           // [Bn][T][4096]
    const unsigned short* __restrict__ whh,  // bf16 [2 dirs][2048][512]
    unsigned short* __restrict__ hbuf,       // bf16 [2 dirs][3 slabs][640][512]
    float* __restrict__ out,                 // [Bn][T][1024] fp32 (or null)
    unsigned short* __restrict__ outb,       // [Bn][T][1024] bf16 (or null)
    int T, unsigned* __restrict__ bar, unsigned base)
{
  __shared__ float preS[NT][4][16][34];      // [nt][gate][n][unit+pad]
  __shared__ float Tr[8][4][4][20];          // [wave][gate][du+pad][n]
  __shared__ unsigned short hS[NT * 16][36]; // [n_local][unit+pad] (write stg)
  __shared__ unsigned short hR[NT * 16][528];// [n_local][unit] (1056B stride)
  const int tid = threadIdx.x;               // 0..511
  const int v = tid >> 6;                    // wave 0..7
  const int l = tid & 63;
  const int d = blockIdx.x >> 4;
  const int w = blockIdx.x & 15;             // slice: units w*32..+31
  const int bg = blockIdx.y;
  const int fr = l & 15;
  const int fq = l >> 4;
  const int ubase = w * 32;
  const int unit = ubase + v * 4 + fq;
  const int nbase = bg * (NT * 16);
  const size_t SLOT = (size_t)640 * 512;
  unsigned* ctr = bar + (d * 8 + bg) * 16;   // 64B-spaced counters
  unsigned short* sl = hbuf + (size_t)d * 3 * SLOT;  // this dir's 3 slabs

  // A-frags: MFMA A row m=fr -> whh row (m>>2)*512 + ubase + v*4 + (m&3)
  s16x8 afr[16];
  {
    const unsigned short* arow = whh + (size_t)d * 2048 * 512 +
        ((size_t)(fr >> 2) * 512 + ubase + v * 4 + (fr & 3)) * 512 + fq * 8;
#pragma unroll
    for (int kk = 0; kk < 16; ++kk)
      afr[kk] = *(const s16x8*)(arow + kk * 32);
  }

  float creg[NT];
#pragma unroll
  for (int i = 0; i < NT; ++i) creg[i] = 0.f;

  // staging thread mapping: one float4 per thread per nt
  const int sc = tid & 7;
  const int sn = (tid >> 3) & 15;
  const int sg = tid >> 7;

  // ---- prologue: pre-clear own stripe in all 3 slabs with LSB=1 ----
  // (first tags used are (t/3)&1 = 0 for t=0,1,2 -> LSB=1 can't false-match)
  for (int s = 0; s < 3; ++s) {
    ulong_t* cb = (ulong_t*)(sl + (size_t)s * SLOT + (size_t)nbase * 512 + ubase);
    for (int i = tid; i < NT * 16 * 8; i += 512)
      __hip_atomic_store(cb + (size_t)(i >> 3) * 128 + (i & 7), LSBM,
                         __ATOMIC_RELAXED, __HIP_MEMORY_SCOPE_AGENT);
  }
  // ---- prologue: stage pre for t=0 ----
  {
    const int tt0 = d ? (T - 1) : 0;
#pragma unroll
    for (int nt = 0; nt < NT; ++nt) {
      const int n = nbase + nt * 16 + sn;
      const float4 pv = *(const float4*)(
          pre + ((size_t)n * T + tt0) * 4096 + d * 2048 + sg * 512 + ubase +
          sc * 4);
      *(float4*)&preS[nt][sg][sn][sc * 4] = pv;
    }
  }
  __syncthreads();  // drains pre-clears (vmcnt0 per wave) + preS lgkm
  // ---- launch-entry barrier: all 16 WGs of (d,bg) pre-cleared ----
  if (tid == 0) {
    __hip_atomic_fetch_add(ctr, 1u, __ATOMIC_RELAXED,
                           __HIP_MEMORY_SCOPE_AGENT);
    const unsigned target = base + 16u;
    long spins = 0;
    while (__hip_atomic_load(ctr, __ATOMIC_RELAXED,
                             __HIP_MEMORY_SCOPE_AGENT) < target) {
      __builtin_amdgcn_s_sleep(1);
      if (++spins > 2000000L) break;  // safety valve
    }
  }
  __syncthreads();

  float hnreg[NT];
  for (int t = 0; t < T; ++t) {
    const int tt = d ? (T - 1 - t) : t;
    const unsigned wtag = (unsigned)((t / 3) & 1);        // tag for h(t)
    unsigned short* wr = sl + (size_t)(t % 3) * SLOT;     // h(t) slab

    // ---- C: direct poll h(t-1) until every bf16 LSB matches rtag ----
    if (t > 0) {
      const unsigned rtag = (unsigned)(((t - 1) / 3) & 1);
      const ulong_t want = rtag ? LSBM : 0ull;
      const ulong_t* hq =
          (const ulong_t*)(sl + (size_t)((t + 2) % 3) * SLOT) +
          (size_t)nbase * 128;
      ulong_t u[4 * NT];
      bool ok = false;
      int it = 0;
      while (!ok && it < 200000) {
#pragma unroll
        for (int i = 0; i < 2 * NT; ++i) {
          const int cid = i * 512 + tid;                 // 16B chunk id
          const ulong_t* p = hq + (size_t)(cid >> 6) * 128 + (cid & 63) * 2;
          u[2 * i] = __hip_atomic_load(p, __ATOMIC_RELAXED,
                                       __HIP_MEMORY_SCOPE_AGENT);
          u[2 * i + 1] = __hip_atomic_load(p + 1, __ATOMIC_RELAXED,
                                           __HIP_MEMORY_SCOPE_AGENT);
        }
        bool bad = false;
#pragma unroll
        for (int i = 0; i < 4 * NT; ++i) bad |= ((u[i] & LSBM) != want);
        ok = !bad;
        ++it;
        if (!ok && it > 12) __builtin_amdgcn_s_sleep(1);
      }
#pragma unroll
      for (int i = 0; i < 2 * NT; ++i) {
        const int cid = i * 512 + tid;
        ulong_t* dst = (ulong_t*)&hR[cid >> 6][(cid & 63) * 8];
        dst[0] = u[2 * i];
        dst[1] = u[2 * i + 1];
      }
    }
    // ---- pv prefetch: pre(t+1) into registers ----
    float4 pv[NT];
    if (t + 1 < T) {
      const int ttn = d ? (T - 2 - t) : (t + 1);
#pragma unroll
      for (int nt = 0; nt < NT; ++nt) {
        const int n = nbase + nt * 16 + sn;
        pv[nt] = *(const float4*)(
            pre + ((size_t)n * T + ttn) * 4096 + d * 2048 + sg * 512 + ubase +
            sc * 4);
      }
    }
    // ---- B1: hR (and E(t-1)'s preS writes) visible to all waves ----
    asm volatile("s_waitcnt lgkmcnt(0)" ::: "memory");
    __builtin_amdgcn_s_barrier();
    __builtin_amdgcn_sched_barrier(0);

    // ---- D: gates + state update ----
#pragma unroll
    for (int nt = 0; nt < NT; ++nt) {
      f32x4 acc = (f32x4){0.f, 0.f, 0.f, 0.f};
      if (t > 0) {
        const unsigned short* bRd = &hR[nt * 16 + fr][fq * 8];
#pragma unroll
        for (int kk = 0; kk < 16; ++kk) {
          const s16x8 bv = *(const s16x8*)(bRd + kk * 32);
          acc = __builtin_amdgcn_mfma_f32_16x16x32_bf16(afr[kk], bv, acc,
                                                        0, 0, 0);
        }
      }
      // wave-local transpose (C row fq*4+r -> gate fq, du r; col fr -> n)
#pragma unroll
      for (int r = 0; r < 4; ++r) Tr[v][fq][r][fr] = acc[r];
      const int uu = v * 4 + fq;
      const float gi = Tr[v][0][fq][fr] + preS[nt][0][fr][uu];
      const float gf = Tr[v][1][fq][fr] + preS[nt][1][fr][uu];
      const float gg = Tr[v][2][fq][fr] + preS[nt][2][fr][uu];
      const float go = Tr[v][3][fq][fr] + preS[nt][3][fr][uu];
      const float cn = sigm(gf) * creg[nt] + sigm(gi) * tanh_f(gg);
      const float hn = sigm(go) * tanh_f(cn);
      creg[nt] = cn;
      hnreg[nt] = hn;
      hS[nt * 16 + fr][uu] =
          (unsigned short)((f2b_one(hn) & 0xFFFEu) | wtag);
    }
    // ---- B2: hS ready; preS fully consumed; hR consumed ----
    asm volatile("s_waitcnt lgkmcnt(0)" ::: "memory");
    __builtin_amdgcn_s_barrier();
    __builtin_amdgcn_sched_barrier(0);

    // ---- E: h stores FIRST (cross-WG critical path), then local work ----
    {
      const int un = tid & 7;       // ulong within 32-unit slice
      const int nl = tid >> 3;      // 0..63
      for (int p = nl; p < NT * 16; p += 64) {
        const ulong_t val = *(const ulong_t*)&hS[p][un * 4];
        __hip_atomic_store(
            (ulong_t*)(wr + (size_t)(nbase + p) * 512 + ubase) + un, val,
            __ATOMIC_RELAXED, __HIP_MEMORY_SCOPE_AGENT);
      }
    }
    if (t + 1 < T) {
#pragma unroll
      for (int nt = 0; nt < NT; ++nt)
        *(float4*)&preS[nt][sg][sn][sc * 4] = pv[nt];
    }
    if (outb) {
      // cooperative coalesced bf16 row stores (64B per row-slice)
      const int un = tid & 7;
      const int nl = tid >> 3;
      for (int p = nl; p < NT * 16; p += 64) {
        const int n = nbase + p;
        const ulong_t val = *(const ulong_t*)&hS[p][un * 4];
        *((ulong_t*)(outb + ((size_t)n * T + tt) * 1024 + d * 512 + ubase) +
          un) = val;
      }
    }
    if (out) {
#pragma unroll
      for (int nt = 0; nt < NT; ++nt) {
        const int n = nbase + nt * 16 + fr;
        out[((size_t)n * T + tt) * 1024 + d * 512 + unit] = hnreg[nt];
      }
    }
  }
}

// ------------------------- column attention pool ----------------------------
__global__ __launch_bounds__(256) void colpool_kernel(
    const float* __restrict__ cenc, const float* __restrict__ caw,
    const float* __restrict__ cab, const float* __restrict__ cmask,
    float* __restrict__ colh)
{
  __shared__ float part[8][33];
  __shared__ float wbuf[8];
  const int p = blockIdx.x;
  const int t = threadIdx.x >> 5;
  const int ln = threadIdx.x & 31;
  const float* row = cenc + ((size_t)p * 8 + t) * 1024;
  float s = 0.f;
  for (int j = ln; j < 1024; j += 32) s += row[j] * caw[j];
  part[t][ln] = s;
  __syncthreads();
  if (threadIdx.x < 8) {
    float lg = 0.f;
    for (int i = 0; i < 32; ++i) lg += part[threadIdx.x][i];
    lg += cab[0];
    wbuf[threadIdx.x] = (cmask[p * 8 + threadIdx.x] > 0.f) ? lg : -INFINITY;
  }
  __syncthreads();
  if (threadIdx.x == 0) {
    float mx = -INFINITY;
    for (int i = 0; i < 8; ++i) mx = fmaxf(mx, wbuf[i]);
    float e[8];
    float sum = 0.f;
    for (int i = 0; i < 8; ++i) { e[i] = __expf(wbuf[i] - mx); sum += e[i]; }
    for (int i = 0; i < 8; ++i) wbuf[i] = e[i] / sum;
  }
  __syncthreads();
  for (int h = threadIdx.x; h < 1024; h += 256) {
    float a = 0.f;
#pragma unroll
    for (int i = 0; i < 8; ++i) a += wbuf[i] * cenc[((size_t)p * 8 + i) * 1024 + h];
    colh[(size_t)p * 1024 + h] = a;
  }
}

// ------------------------- gather observed ----------------------------------
__global__ __launch_bounds__(256) void gather_kernel(
    const float* __restrict__ colh, const int* __restrict__ gold_num,
    const int* __restrict__ gold_cols, const int* __restrict__ ncol,
    float* __restrict__ obs)
{
  const int idx = blockIdx.x * 256 + threadIdx.x;
  const int h = idx & 1023;
  const int k = (idx >> 10) & 3;
  const int b = idx >> 12;
  int gn = gold_num[b];
  if (gn > 4) gn = 4;
  const float m = (k < gn) ? 1.f : 0.f;
  const int col = gold_cols[b * 4 + k];
  const int NC = ncol[0];
  obs[idx] = m * colh[(size_t)(b * NC + col) * 1024 + h];
}

// ------------------------- fused attention (per b,k) ------------------------
__global__ __launch_bounds__(128) void attn_kernel(
    const float* __restrict__ akey, const float* __restrict__ qenc,
    const float* __restrict__ qmask, float* __restrict__ qhid)
{
  __shared__ float ak[1024];
  __shared__ float red[128];
  __shared__ float at[128];
  const int bk = blockIdx.x;
  const int b = bk >> 2;
  const int tid = threadIdx.x;
  for (int i = tid; i < 1024; i += 128) ak[i] = akey[(size_t)bk * 1024 + i];
  __syncthreads();
  const float* qrow = qenc + ((size_t)b * 128 + tid) * 1024;
  float s = 0.f;
  for (int hh = 0; hh < 1024; hh += 4) {
    const float4 qv = *(const float4*)(qrow + hh);
    s += ak[hh] * qv.x + ak[hh + 1] * qv.y + ak[hh + 2] * qv.z + ak[hh + 3] * qv.w;
  }
  s = (qmask[b * 128 + tid] > 0.f) ? s : -INFINITY;
  at[tid] = s;
  red[tid] = s;
  __syncthreads();
  for (int off = 64; off > 0; off >>= 1) {
    if (tid < off) red[tid] = fmaxf(red[tid], red[tid + off]);
    __syncthreads();
  }
  const float mx = red[0];
  __syncthreads();
  const float e = __expf(at[tid] - mx);
  red[tid] = e;
  __syncthreads();
  for (int off = 64; off > 0; off >>= 1) {
    if (tid < off) red[tid] += red[tid + off];
    __syncthreads();
  }
  const float inv = 1.f / red[0];
  __syncthreads();
  at[tid] = e * inv;
  __syncthreads();
  for (int h = tid; h < 1024; h += 128) {
    float a = 0.f;
    for (int q = 0; q < 128; ++q)
      a += at[q] * qenc[((size_t)b * 128 + q) * 1024 + h];
    qhid[(size_t)bk * 1024 + h] = a;
  }
}

// ------------------------- final epilogue -----------------------------------
__global__ __launch_bounds__(64) void final_kernel(
    const float* __restrict__ A, const float* __restrict__ Bm,
    const float* __restrict__ w2, const float* __restrict__ b2,
    const int* __restrict__ gold_num, const float* __restrict__ qmask,
    float* __restrict__ out)
{
  const int bkq = blockIdx.x;
  const int q = bkq & 127;
  const int k = (bkq >> 7) & 3;
  const int b = bkq >> 9;
  int gn = gold_num[b];
  if (gn > 4) gn = 4;
  const bool act = (k < gn) && (qmask[b * 128 + q] > 0.f);
  const int lane = threadIdx.x;
  const int obase = (b * 4 + k) * 128 + q;
  if (!act) {
    if (lane == 0) {
      out[obase] = -1e30f;          // finite sentinel (ref has -inf; see r1)
      out[16384 + obase] = -1e30f;
    }
    return;
  }
  const float* Ar = A + ((size_t)b * 128 + q) * 1024;
  const float* Br = Bm + (size_t)(b * 4 + k) * 1024;
  float s0 = 0.f, s1 = 0.f;
  for (int o = lane; o < 1024; o += 64) {
    const float v = tanh_f(Ar[o] + Br[o]);
    s0 += v * w2[o];
    s1 += v * w2[1024 + o];
  }
#pragma unroll
  for (int off = 32; off > 0; off >>= 1) {
    s0 += __shfl_down(s0, off, 64);
    s1 += __shfl_down(s1, off, 64);
  }
  if (lane == 0) {
    out[obase] = s0 + b2[0];
    out[16384 + obase] = s1 + b2[1];
  }
}

// ---------------------------------------------------------------------------
extern "C" void kernel_launch(void* const* d_in, const int* in_sizes, int n_in,
                              void* d_out, int out_size, void* d_ws, size_t ws_size,
                              hipStream_t stream)
{
  const float* qe      = (const float*)d_in[0];
  const float* pce     = (const float*)d_in[1];
  const int* gold_num  = (const int*)d_in[2];
  const int* gold_cols = (const int*)d_in[3];
  const int* ncol      = (const int*)d_in[5];
  const float* q_Wih   = (const float*)d_in[6];
  const float* q_Whh   = (const float*)d_in[7];
  const float* q_b     = (const float*)d_in[8];
  const float* c_Wih   = (const float*)d_in[9];
  const float* c_Whh   = (const float*)d_in[10];
  const float* c_b     = (const float*)d_in[11];
  const float* caw     = (const float*)d_in[12];
  const float* cab     = (const float*)d_in[13];
  const float* obaW    = (const float*)d_in[14];
  const float* obab    = (const float*)d_in[15];
  const float* obcW    = (const float*)d_in[16];
  const float* obcb    = (const float*)d_in[17];
  const float* qpW     = (const float*)d_in[18];
  const float* qpb     = (const float*)d_in[19];
  const float* o1W     = (const float*)d_in[20];
  const float* o1b     = (const float*)d_in[21];
  const float* o2W     = (const float*)d_in[22];
  const float* o2b     = (const float*)d_in[23];
  float* outp = (float*)d_out;

  float* ws = (float*)d_ws;
  size_t off = 0;
  float* pre  = ws + off; off += 640UL * 8 * 4096;   // also reused as A matrix
  float* bufA = ws + off; off += 640UL * 8 * 1024;   // (unused after fusion)
  float* bufB = ws + off; off += 640UL * 8 * 1024;
  float* colh = ws + off; off += 640UL * 1024;
  float* qmask = ws + off; off += 4096;
  float* cmask = ws + off; off += 5120;
  float* obs  = ws + off; off += 131072;
  float* akey = ws + off; off += 131072;
  float* qhid = ws + off; off += 131072;
  float* vec  = ws + off; off += 262144;
  float* Bm   = ws + off; off += 131072;
  unsigned short* xb = (unsigned short*)(ws + off); off += 2621440;  // bf16 acts
  unsigned short* wb = (unsigned short*)(ws + off); off += 2097152;  // bf16 Wih
  unsigned short* whhq = (unsigned short*)(ws + off); off += 2097152; // q_Whh bf16
  unsigned short* whhc = (unsigned short*)(ws + off); off += 2097152; // c_Whh bf16
  unsigned short* hbuf = (unsigned short*)(ws + off); off += 983040;  // 2 dirs x 3 slabs
  unsigned* bar = (unsigned*)(ws + off); off += 256;  // 16 counters x 64B
  float* Amat = pre;
  (void)bufA;

  const dim3 blk(256);
  auto cvt = [&](const float* src, unsigned short* dst, int n) {
    hipLaunchKernelGGL(f2b_kernel, dim3((n / 4 + 255) / 256), blk, 0, stream,
                       src, dst, n / 4);
  };

  // counters must start at 0 every call (ws is poisoned 0xAA)
  hipMemsetAsync(bar, 0, 1024, stream);

  hipLaunchKernelGGL(mask_kernel, dim3(2304), blk, 0, stream, qe, pce, qmask, cmask);

  // recurrent weights -> bf16 (once)
  cvt(q_Whh, whhq, 4194304);
  cvt(c_Whh, whhc, 4194304);

  // ---- column biLSTM (B=640, T=8): grid (32,8), NT=5 ----
  // layer 0: input cvt; scan emits bf16 directly into xb (no fp32 out)
  cvt(pce, xb, 5242880);
  cvt(c_Wih, wb, 4194304);
  hipLaunchKernelGGL(mfma_gemm_kernel, dim3(4096 / 128, 5120 / 128), blk, 0,
                     stream, xb, wb, c_b, pre, 1024, 1024, 1024, 0, 4096, 0);
  hipLaunchKernelGGL((lstm_seq_kernel<5>), dim3(32, 8), dim3(512), 0, stream,
                     pre, whhc, hbuf, (float*)nullptr, xb, 8, bar, 0u);
  // layer 1: reads xb (bf16 from scan); emits fp32 bufB only
  cvt(c_Wih + 4194304, wb, 4194304);
  hipLaunchKernelGGL(mfma_gemm_kernel, dim3(4096 / 128, 5120 / 128), blk, 0,
                     stream, xb, wb, c_b + 4096, pre, 1024, 1024, 1024, 0, 4096, 0);
  hipLaunchKernelGGL((lstm_seq_kernel<5>), dim3(32, 8), dim3(512), 0, stream,
                     pre, whhc + (size_t)2 * 2048 * 512, hbuf, bufB,
                     (unsigned short*)nullptr, 8, bar, 16u);
  hipLaunchKernelGGL(colpool_kernel, dim3(640), blk, 0, stream,
                     bufB, caw, cab, cmask, colh);
  hipLaunchKernelGGL(gather_kernel, dim3(512), blk, 0, stream,
                     colh, gold_num, gold_cols, ncol, obs);

  // ---- question biLSTM (B=32, T=128): grid (32,1), NT=2 ----
  // layer 0: input cvt; scan emits bf16 into xb only
  cvt(qe, xb, 4194304);
  cvt(q_Wih, wb, 4194304);
  hipLaunchKernelGGL(mfma_gemm_kernel, dim3(4096 / 128, 4096 / 128), blk, 0,
                     stream, xb, wb, q_b, pre, 1024, 1024, 1024, 0, 4096, 0);
  hipLaunchKernelGGL((lstm_seq_kernel<2>), dim3(32, 1), dim3(512), 0, stream,
                     pre, whhq, hbuf, (float*)nullptr, xb, 128, bar, 32u);
  // layer 1: reads xb; emits fp32 bufB (attn/gemms) + bf16 xb (o1 GEMM)
  cvt(q_Wih + 4194304, wb, 4194304);
  hipLaunchKernelGGL(mfma_gemm_kernel, dim3(4096 / 128, 4096 / 128), blk, 0,
                     stream, xb, wb, q_b + 4096, pre, 1024, 1024, 1024, 0, 4096, 0);
  hipLaunchKernelGGL((lstm_seq_kernel<2>), dim3(32, 1), dim3(512), 0, stream,
                     pre, whhq + (size_t)2 * 2048 * 512, hbuf, bufB, xb,
                     128, bar, 48u);
  const float* qenc = bufB;

  // att_key = observed @ ob_attn_W^T + b   (small, fp32 path)
  hipLaunchKernelGGL(gemm_kernel, dim3(16, 2), blk, 0, stream,
                     obs, obaW, obab, akey, 128, 1024, 1024, 1024, 1024, 0, 1024, 0);
  hipLaunchKernelGGL(attn_kernel, dim3(128), dim3(128), 0, stream,
                     akey, qenc, qmask, qhid);
  hipLaunchKernelGGL(gemm_kernel, dim3(16, 2), blk, 0, stream,
                     obs, obcW, obcb, vec, 128, 1024, 1024, 1024, 1024, 0, 2048, 0);
  hipLaunchKernelGGL(gemm_kernel, dim3(16, 2), blk, 0, stream,
                     qhid, qpW, qpb, vec, 128, 1024, 1024, 1024, 1024, 0, 2048, 1024);
  // A = qenc @ out1_W[:, :1024]^T + b1  (bf16 MFMA; xb = qenc bf16 from scan)
  cvt(o1W, wb, 3145728);
  hipLaunchKernelGGL(mfma_gemm_kernel, dim3(1024 / 128, 4096 / 128), blk, 0,
                     stream, xb, wb, o1b, Amat, 1024, 1024, 3072, 0, 1024, 0);
  // Bm = vec @ out1_W[:, 1024:]^T (fp32 path)
  hipLaunchKernelGGL(gemm_kernel, dim3(16, 2), blk, 0, stream,
                     vec, o1W, nullptr, Bm, 128, 1024, 2048, 2048, 3072, 1024, 1024, 0);
  hipLaunchKernelGGL(final_kernel, dim3(16384), dim3(64), 0, stream,
                     Amat, Bm, o2W, o2b, gold_num, qmask, outp);
}